// Round 9
// baseline (1554.790 us; speedup 1.0000x reference)
//
#include <hip/hip_runtime.h>
#include <hip/hip_bf16.h>

// ---------------- constants ----------------
#define B_    16
#define SL_   512
#define S_    511
#define E_    256
#define NH_   4
#define I_    512
#define DHM_  128
#define DHS_  64
#define F_    384
#define NP_   8192               // padded row count (multiple of 64)
#define NROW  (B_*S_)            // 8176 real rows
#define EPS_  1e-5f

typedef __hip_bfloat16 bf16;
typedef __bf16 bf16x8v __attribute__((ext_vector_type(8)));
typedef float  f32x4v  __attribute__((ext_vector_type(4)));

__device__ __forceinline__ float sig_(float x){ return 1.f/(1.f+__expf(-x)); }
__device__ __forceinline__ float silu_(float x){ return x*sig_(x); }
__device__ __forceinline__ float logsig_(float x){ return fminf(x,0.f) - log1pf(__expf(-fabsf(x))); }
__device__ __forceinline__ float expneg_(float x){ return __expf(fminf(x,0.f)); }
__device__ __forceinline__ float expclamp_(float x){ return __expf(fminf(fmaxf(x,-80.f),80.f)); }
__device__ __forceinline__ float tanh_(float x){ return 1.f - 2.f/(__expf(2.f*x)+1.f); }

// ---------------- f32 -> bf16 weight conversion ----------------
__global__ __launch_bounds__(256) void k_cvt16(const float* __restrict__ src, bf16* __restrict__ dst, int n){
  int i=blockIdx.x*256+threadIdx.x;
  if(i<n) dst[i]=__float2bfloat16(src[i]);
}

// ---------------- embedding gather + fused LN0 ----------------
__global__ __launch_bounds__(256) void k_embed(
  const int* __restrict__ questions, const int* __restrict__ responses, const int* __restrict__ skills,
  const float* __restrict__ q_embed, const float* __restrict__ qa_embed,
  const float* __restrict__ q_embed_diff, const float* __restrict__ qa_embed_diff,
  const float* __restrict__ difficult_param, const float* __restrict__ ln0w,
  float* __restrict__ x, float* __restrict__ qe, float* __restrict__ h,
  float* __restrict__ pide, int* __restrict__ tgt, int* __restrict__ qsh)
{
  __shared__ float red[256];
  int r = blockIdx.x; int e = threadIdx.x;
  float xa = 0.f;
  if (r < NROW){
    int b = r / S_, s = r % S_;
    int pid  = questions[b*SL_+s];
    int qd   = skills[b*SL_+s];
    int resp = responses[b*SL_+s];
    int t    = (resp > -1) ? resp : 0;
    float pe = difficult_param[pid];
    float q0 = q_embed[qd*E_+e];
    xa = q0 + qa_embed[t*E_+e] + pe*qa_embed_diff[t*E_+e];
    float qn = q0 + pe*q_embed_diff[qd*E_+e];
    x[(size_t)r*E_+e]=xa; qe[(size_t)r*E_+e]=qn;
    if (e==0){ pide[r]=pe; tgt[r]=t; qsh[r]=skills[b*SL_+s+1]; }
  } else {
    x[(size_t)r*E_+e]=0.f; qe[(size_t)r*E_+e]=0.f;
    if (e==0){ pide[r]=0.f; tgt[r]=-7; qsh[r]=0; }
  }
  red[e]=xa; __syncthreads();
  for(int s2=128;s2>0;s2>>=1){ if(e<s2) red[e]+=red[e+s2]; __syncthreads(); }
  float mu = red[0]*(1.f/E_); __syncthreads();
  float d = xa-mu;
  red[e]=d*d; __syncthreads();
  for(int s2=128;s2>0;s2>>=1){ if(e<s2) red[e]+=red[e+s2]; __syncthreads(); }
  float var = red[0]*(1.f/E_);
  h[(size_t)r*E_+e] = d*rsqrtf(var+EPS_)*ln0w[e];
}

// ---------------- layernorm over E=256 (used for ln1) ----------------
__global__ __launch_bounds__(256) void k_ln(
  const float* __restrict__ in, const float* __restrict__ w, float* __restrict__ out)
{
  __shared__ float red[256];
  int r = blockIdx.x, t = threadIdx.x;
  float v = in[(size_t)r*E_+t];
  red[t]=v; __syncthreads();
  for(int s=128;s>0;s>>=1){ if(t<s) red[t]+=red[t+s]; __syncthreads(); }
  float mu = red[0]*(1.f/E_); __syncthreads();
  float d = v-mu;
  red[t]=d*d; __syncthreads();
  for(int s=128;s>0;s>>=1){ if(t<s) red[t]+=red[t+s]; __syncthreads(); }
  float var = red[0]*(1.f/E_);
  out[(size_t)r*E_+t] = d*rsqrtf(var+EPS_)*w[t];
}

// ---------------- f32 GEMM (kept for m_up only) ----------------
__global__ __launch_bounds__(256) void k_gemm(
  const float* __restrict__ A, int lda,
  const float* __restrict__ Bw, const float* __restrict__ bias,
  float* __restrict__ C, int M, int K, int relu)
{
  __shared__ __align__(16) float As[16][68];
  __shared__ __align__(16) float Bs[16][68];
  int tid = threadIdx.x;
  int row0 = blockIdx.y*64, col0 = blockIdx.x*64;
  int tm=(tid/16)*4, tn=(tid%16)*4;
  int lk=tid%16, lm=tid/16;
  float acc[4][4]={};
  for(int k0=0;k0<K;k0+=16){
    #pragma unroll
    for(int i=0;i<4;i++){
      int m=lm+i*16;
      As[lk][m]=A[(size_t)(row0+m)*lda + k0+lk];
      Bs[lk][m]=Bw[(size_t)(col0+m)*K + k0+lk];
    }
    __syncthreads();
    #pragma unroll
    for(int k=0;k<16;k++){
      float4 a=*(const float4*)&As[k][tm];
      float4 b=*(const float4*)&Bs[k][tn];
      float av[4]={a.x,a.y,a.z,a.w};
      float bv[4]={b.x,b.y,b.z,b.w};
      #pragma unroll
      for(int i=0;i<4;i++)
        #pragma unroll
        for(int j=0;j<4;j++) acc[i][j]+=av[i]*bv[j];
    }
    __syncthreads();
  }
  #pragma unroll
  for(int i=0;i<4;i++){
    #pragma unroll
    for(int j=0;j<4;j++){
      float v=acc[i][j] + (bias? bias[col0+tn+j] : 0.f);
      if(relu) v=fmaxf(v,0.f);
      C[(size_t)(row0+tm+i)*M + col0+tn+j]=v;
    }
  }
}

// ---------------- bf16 MFMA GEMM (+ optional residual) ----------------
__global__ __launch_bounds__(256) void k_gemm16(
  const bf16* __restrict__ A, const bf16* __restrict__ Bw,
  const float* __restrict__ bias, const float* __restrict__ resid,
  float* __restrict__ C, bf16* __restrict__ C16,
  int M, int K, int relu)
{
  int tid=threadIdx.x;
  int wave=tid>>6, lane=tid&63;
  int wr=wave>>1, wc=wave&1;
  int row0=blockIdx.y*64 + wr*32;
  int col0=blockIdx.x*64 + wc*32;
  int lrow = lane&15, lq = lane>>4;
  f32x4v acc[2][2] = {};
  const bf16* Abase = A  + (size_t)(row0+lrow)*K + lq*8;
  const bf16* Bbase = Bw + (size_t)(col0+lrow)*K + lq*8;
  for(int k0=0;k0<K;k0+=32){
    bf16x8v a0 = *(const bf16x8v*)(Abase + k0);
    bf16x8v a1 = *(const bf16x8v*)(Abase + (size_t)16*K + k0);
    bf16x8v b0 = *(const bf16x8v*)(Bbase + k0);
    bf16x8v b1 = *(const bf16x8v*)(Bbase + (size_t)16*K + k0);
    acc[0][0]=__builtin_amdgcn_mfma_f32_16x16x32_bf16(a0,b0,acc[0][0],0,0,0);
    acc[0][1]=__builtin_amdgcn_mfma_f32_16x16x32_bf16(a0,b1,acc[0][1],0,0,0);
    acc[1][0]=__builtin_amdgcn_mfma_f32_16x16x32_bf16(a1,b0,acc[1][0],0,0,0);
    acc[1][1]=__builtin_amdgcn_mfma_f32_16x16x32_bf16(a1,b1,acc[1][1],0,0,0);
  }
  #pragma unroll
  for(int mi=0;mi<2;mi++){
    #pragma unroll
    for(int ni=0;ni<2;ni++){
      #pragma unroll
      for(int r=0;r<4;r++){
        int row=row0+mi*16+lq*4+r;       // C/D: col=lane&15, row=(lane>>4)*4+reg  [m89]
        int col=col0+ni*16+lrow;
        float v=acc[mi][ni][r] + (bias? bias[col]:0.f);
        if(relu) v=fmaxf(v,0.f);
        if(resid) v += resid[(size_t)row*M+col];
        if(C)   C[(size_t)row*M+col]=v;
        if(C16) C16[(size_t)row*M+col]=__float2bfloat16(v);
      }
    }
  }
}

// ---------------- causal depthwise conv K=4 + silu ----------------
__global__ __launch_bounds__(256) void k_conv_silu(
  const float* __restrict__ in, int ild, const float* __restrict__ w, const float* __restrict__ bws,
  float* __restrict__ out, int old_, int C)
{
  int i = blockIdx.x*256 + threadIdx.x;
  int r = i / C, c = i % C;
  if (r >= NP_) return;
  float acc = 0.f;
  if (r < NROW) {
    int b=r/S_, s=r%S_;
    acc = bws[c];
    #pragma unroll
    for(int j=0;j<4;j++){
      int ss=s-3+j;
      if(ss>=0) acc += w[c*4+j] * in[(size_t)(b*S_+ss)*ild + c];
    }
    acc = silu_(acc);
  }
  out[(size_t)r*old_ + c] = acc;
}

// ---------------- headwise 4x4 block projections q,k,v ----------------
__global__ __launch_bounds__(256) void k_headwise(
  const float* __restrict__ xc, const float* __restrict__ xm, int xmld,
  const float* __restrict__ wq, const float* __restrict__ wk, const float* __restrict__ wv,
  float* __restrict__ q, float* __restrict__ k, float* __restrict__ v)
{
  int i=blockIdx.x*256+threadIdx.x;
  int r=i/I_, c=i%I_;
  if(r>=NP_) return;
  size_t oi=(size_t)r*I_+c;
  if(r>=NROW){ q[oi]=0.f; k[oi]=0.f; v[oi]=0.f; return; }
  int n=c>>2, o=c&3;
  const float* xcr = xc + (size_t)r*I_ + n*4;
  const float* xmr = xm + (size_t)r*xmld + n*4;
  float aq=0.f, ak=0.f, av=0.f;
  #pragma unroll
  for(int d=0;d<4;d++){
    float xcv=xcr[d], xmv=xmr[d];
    aq += xcv*wq[(n*4+o)*4+d];
    ak += xcv*wk[(n*4+o)*4+d];
    av += xmv*wv[(n*4+o)*4+d];
  }
  q[oi]=aq; k[oi]=ak; v[oi]=av;
}

// ---------------- ig/fg gates ----------------
__global__ __launch_bounds__(256) void k_igfg(
  const float* __restrict__ q, const float* __restrict__ k, const float* __restrict__ v,
  const float* __restrict__ wig, const float* __restrict__ big,
  const float* __restrict__ wfg, const float* __restrict__ bfg,
  float* __restrict__ igb, float* __restrict__ fgb)
{
  int r=blockIdx.x;
  int wid=threadIdx.x>>6, lane=threadIdx.x&63;
  int b=r/S_, s=r%S_;
  for(int c=wid; c<8; c+=4){
    int h=c>>1; int isfg=c&1;
    const float* w = isfg? wfg : wig;
    float acc=0.f;
    for(int f=lane; f<1536; f+=64){
      float val = (f<512)? q[(size_t)r*512+f]
                : (f<1024)? k[(size_t)r*512+f-512]
                : v[(size_t)r*512+f-1024];
      acc += val*w[h*1536+f];
    }
    for(int m=32;m;m>>=1) acc+=__shfl_xor(acc,m,64);
    if(lane==0){
      if(isfg) fgb[(b*4+h)*512+s]=acc+bfg[h];
      else     igb[(b*4+h)*512+s]=acc+big[h];
    }
  }
}

// ---------------- decay prep (parallel scans): one block per bh ----------------
__global__ __launch_bounds__(256) void k_decay(
  const float* __restrict__ igb, const float* __restrict__ fgb,
  float* __restrict__ cs1, float* __restrict__ g, float* __restrict__ M)
{
  int bh = blockIdx.x; int tid = threadIdx.x;
  __shared__ float buf[512];
  __shared__ float buf2[512];
  for (int s=tid; s<512; s+=256)
    buf[s] = (s<S_) ? logsig_(fgb[bh*512+s]) : 0.f;
  __syncthreads();
  for (int off=1; off<512; off<<=1){
    int s0=tid, s1=tid+256;
    float v0 = buf[s0] + ((s0>=off)? buf[s0-off] : 0.f);
    float v1 = buf[s1] + ((s1>=off)? buf[s1-off] : 0.f);
    __syncthreads();
    buf[s0]=v0; buf[s1]=v1;
    __syncthreads();
  }
  for (int s=tid; s<512; s+=256){
    float c = buf[s];
    if (s<S_){
      cs1[bh*512+s]=c;
      float gv = igb[bh*512+s]-c;
      g[bh*512+s]=gv;
      buf2[s]=gv;
    } else buf2[s] = -3.4e38f;
  }
  __syncthreads();
  for (int off=1; off<512; off<<=1){
    int s0=tid, s1=tid+256;
    float v0 = fmaxf(buf2[s0], (s0>=off)? buf2[s0-off] : -3.4e38f);
    float v1 = fmaxf(buf2[s1], (s1>=off)? buf2[s1-off] : -3.4e38f);
    __syncthreads();
    buf2[s0]=v0; buf2[s1]=v1;
    __syncthreads();
  }
  for (int s=tid; s<S_; s+=256) M[bh*512+s] = buf2[s];
}

// ---------------- tiled attention (unchanged) ----------------
#define TQ 32
#define TS 32
__global__ __launch_bounds__(256) void k_attn(
  const float* __restrict__ q, const float* __restrict__ k, const float* __restrict__ v,
  const float* __restrict__ cs1, const float* __restrict__ g, const float* __restrict__ M,
  const float* __restrict__ onw, float* __restrict__ hflat)
{
  __shared__ __align__(16) float qs[TQ][132];
  __shared__ __align__(16) float ks[TS][132];
  __shared__ __align__(16) float vs[TS][128];
  __shared__ float Sw[TQ][33];
  __shared__ float MtS[TQ], cssS[TQ], lsumS[TQ], gsS[TS];
  int tq = blockIdx.x, bh = blockIdx.y;
  int b = bh>>2, h = bh&3;
  int tid = threadIdx.x;
  int i = tid>>4, j = tid&15;
  int t0 = tq*TQ;
  {
    int row = tid>>3, c4 = (tid&7)*4;
    const float4* src = (const float4*)(q + (size_t)(b*S_ + t0 + row)*512 + h*128);
    float4* dst = (float4*)&qs[row][0];
    #pragma unroll
    for(int c=0;c<4;c++) dst[c4+c] = src[c4+c];
  }
  if (tid < TQ){
    int t = t0 + tid; int tc = (t<S_)? t : (S_-1);
    MtS[tid]  = M[bh*512 + tc];
    cssS[tid] = cs1[bh*512 + tc];
    lsumS[tid]= 0.f;
  }
  float o[2][8] = {};
  int t1 = min(t0+TQ, S_);
  int nst = (t1 + TS - 1)/TS;
  const float sc = 0.08838834764831843f;
  for (int st=0; st<nst; ++st){
    int s0 = st*TS;
    __syncthreads();
    {
      int row = tid>>3, c4 = (tid&7)*4;
      const float4* srck = (const float4*)(k + (size_t)(b*S_ + s0 + row)*512 + h*128);
      const float4* srcv = (const float4*)(v + (size_t)(b*S_ + s0 + row)*512 + h*128);
      float4* dk = (float4*)&ks[row][0];
      float4* dv = (float4*)&vs[row][0];
      #pragma unroll
      for(int c=0;c<4;c++){ dk[c4+c]=srck[c4+c]; dv[c4+c]=srcv[c4+c]; }
      if (tid < TS) gsS[tid] = g[bh*512 + s0 + tid];
    }
    __syncthreads();
    float a00=0,a01=0,a10=0,a11=0;
    {
      const float4* q0 = (const float4*)&qs[i*2][0];
      const float4* q1 = (const float4*)&qs[i*2+1][0];
      const float4* k0 = (const float4*)&ks[j][0];
      const float4* k1 = (const float4*)&ks[j+16][0];
      #pragma unroll
      for(int d4=0; d4<32; ++d4){
        float4 qa=q0[d4], qb=q1[d4], ka=k0[d4], kb=k1[d4];
        a00 += qa.x*ka.x+qa.y*ka.y+qa.z*ka.z+qa.w*ka.w;
        a01 += qa.x*kb.x+qa.y*kb.y+qa.z*kb.z+qa.w*kb.w;
        a10 += qb.x*ka.x+qb.y*ka.y+qb.z*ka.z+qb.w*ka.w;
        a11 += qb.x*kb.x+qb.y*kb.y+qb.z*kb.z+qb.w*kb.w;
      }
    }
    int tA = t0 + i*2, tB = tA+1;
    int sA = s0 + j,   sB = sA + 16;
    float gA = gsS[j], gB = gsS[j+16];
    float mA = MtS[i*2], mB = MtS[i*2+1];
    float w00 = (sA<=tA)? a00*sc*expneg_(gA-mA) : 0.f;
    float w01 = (sB<=tA)? a01*sc*expneg_(gB-mA) : 0.f;
    float w10 = (sA<=tB)? a10*sc*expneg_(gA-mB) : 0.f;
    float w11 = (sB<=tB)? a11*sc*expneg_(gB-mB) : 0.f;
    float r0 = w00+w01, r1 = w10+w11;
    #pragma unroll
    for(int msk=1; msk<16; msk<<=1){ r0 += __shfl_xor(r0,msk,16); r1 += __shfl_xor(r1,msk,16); }
    if (j==0){ lsumS[i*2] += r0; lsumS[i*2+1] += r1; }
    Sw[i*2][j]     = w00; Sw[i*2][j+16]   = w01;
    Sw[i*2+1][j]   = w10; Sw[i*2+1][j+16] = w11;
    __syncthreads();
    #pragma unroll 8
    for(int s=0;s<TS;s++){
      float w0 = Sw[i*2][s], w1 = Sw[i*2+1][s];
      float4 v0 = *(const float4*)&vs[s][j*4];
      float4 v1 = *(const float4*)&vs[s][64+j*4];
      o[0][0]+=w0*v0.x; o[0][1]+=w0*v0.y; o[0][2]+=w0*v0.z; o[0][3]+=w0*v0.w;
      o[0][4]+=w0*v1.x; o[0][5]+=w0*v1.y; o[0][6]+=w0*v1.z; o[0][7]+=w0*v1.w;
      o[1][0]+=w1*v0.x; o[1][1]+=w1*v0.y; o[1][2]+=w1*v0.z; o[1][3]+=w1*v0.w;
      o[1][4]+=w1*v1.x; o[1][5]+=w1*v1.y; o[1][6]+=w1*v1.z; o[1][7]+=w1*v1.w;
    }
  }
  __syncthreads();
  #pragma unroll
  for(int r=0;r<2;r++){
    int tl = i*2+r;
    int t = t0 + tl;
    float maxD = cssS[tl] + MtS[tl];
    float norm = fmaxf(fabsf(lsumS[tl]), expclamp_(-maxD));
    float scale = 1.f/(norm+1e-6f);
    float sum=0.f;
    #pragma unroll
    for(int d=0;d<8;d++){ o[r][d]*=scale; sum+=o[r][d]; }
    #pragma unroll
    for(int msk=1; msk<16; msk<<=1) sum += __shfl_xor(sum,msk,16);
    float mu = sum*(1.f/128.f);
    float var=0.f;
    #pragma unroll
    for(int d=0;d<8;d++){ float dd=o[r][d]-mu; var+=dd*dd; }
    #pragma unroll
    for(int msk=1; msk<16; msk<<=1) var += __shfl_xor(var,msk,16);
    float rs = rsqrtf(var*(1.f/128.f)+EPS_);
    if (t < S_){
      float* dst = hflat + (size_t)(b*S_+t)*1024 + h*128;
      #pragma unroll
      for(int c=0;c<4;c++) dst[j*4+c]    = (o[r][c]  -mu)*rs*onw[h*128+j*4+c];
      #pragma unroll
      for(int c=0;c<4;c++) dst[64+j*4+c] = (o[r][4+c]-mu)*rs*onw[h*128+64+j*4+c];
    }
  }
}

// ---------------- hout = (hflat + skip*xc) * silu(z) -> bf16 ----------------
__global__ __launch_bounds__(256) void k_hout(
  const float* __restrict__ A, const float* __restrict__ xc, const float* __restrict__ skip,
  bf16* __restrict__ out16)
{
  int i=blockIdx.x*256+threadIdx.x;
  int r=i/512, c=i%512;
  float hf=A[(size_t)r*1024+c];
  float z =A[(size_t)r*1024+512+c];
  out16[(size_t)r*512+c] = __float2bfloat16((hf + skip[c]*xc[(size_t)r*512+c]) * silu_(z));
}

// ---------------- wx = gate pre-activations, scan layout [bn][s][g*64+e] ----------------
__global__ __launch_bounds__(256) void k_wx(
  const float* __restrict__ h, const float* __restrict__ hc,
  const float* __restrict__ gw, const float* __restrict__ gb,
  float* __restrict__ wx)
{
  __shared__ float hs[256], hcs[256];
  int r=blockIdx.x; int t=threadIdx.x;
  hs[t]=h[(size_t)r*256+t]; hcs[t]=hc[(size_t)r*256+t];
  __syncthreads();
  int b=r/S_, s=r%S_;
  int n=t>>6, e=t&63;
  #pragma unroll
  for(int gg=0; gg<4; gg++){
    const float* src = (gg<2? hcs: hs) + n*64;
    const float* wp = gw + (size_t)(((gg*4+n)*64+e))*64;
    float acc=gb[(gg*4+n)*64+e];
    #pragma unroll 8
    for(int d=0;d<64;d++) acc+=src[d]*wp[d];
    wx[((size_t)(b*4+n)*512 + s)*256 + gg*64 + e]=acc;
  }
}

// ---------------- sLSTM scan: self-contained waves, shfl transpose, ONE barrier/step ----------------
// wave w owns elements [16w,16w+16); lane L = (gate gl=L>>4, element el=16w+(L&15)).
// After matvec, gates of element el live in lanes L,L^16,L^32,L^48 -> 3 shfl_xor,
// gate chain computed redundantly in all 4 subgroups; gl==0 writes ping-pong yS.
#define YCH 32
__global__ __launch_bounds__(256,1) void k_scan(
  const float* __restrict__ wx, const float* __restrict__ rw, float* __restrict__ y_out)
{
  int bn = blockIdx.x; int b = bn>>2, n = bn&3;
  int tid = threadIdx.x;
  int wave = tid>>6, L = tid&63;
  int gl = L>>4;
  int el = (wave<<4) + (L&15);
  float W[64];
  #pragma unroll
  for(int d=0;d<64;d++) W[d]=rw[(size_t)(((gl*4+n)*64+d))*64 + el];
  __shared__ __align__(16) float yS[2][64];
  __shared__ __align__(16) float wxS[2][YCH*256];
  __shared__ float ybuf[YCH*64];
  const float* wxBase = wx + (size_t)bn*512*256;
  { // stage chunk 0
    const float4* src=(const float4*)wxBase;
    float4* dst=(float4*)&wxS[0][0];
    #pragma unroll
    for(int j=0;j<8;j++) dst[j*256+tid]=src[j*256+tid];
  }
  if (tid<64) yS[0][tid]=0.f;
  __syncthreads();
  float c=0.f, nn=0.f, m=0.f;
  for (int s=0; s<S_; ++s){
    int sl = s & (YCH-1);
    int rb = s&1, wb = rb^1;
    float wxv = wxS[(s>>5)&1][sl*256 + (gl<<6) + el];
    float a0=0,a1=0,a2=0,a3=0;
    const float4* y4=(const float4*)&yS[rb][0];
    #pragma unroll
    for(int d=0;d<16;d++){
      float4 yv=y4[d];
      a0+=yv.x*W[4*d]; a1+=yv.y*W[4*d+1]; a2+=yv.z*W[4*d+2]; a3+=yv.w*W[4*d+3];
    }
    float self = wxv + ((a0+a1)+(a2+a3));
    float vA = __shfl_xor(self, 16, 64);   // gate gl^1, same element
    float vB = __shfl_xor(self, 32, 64);   // gate gl^2
    float vC = __shfl_xor(vA,   32, 64);   // gate gl^3
    float iraw = (gl==0)? self : (gl==1)? vA : (gl==2)? vB : vC;
    float fraw = (gl==0)? vA   : (gl==1)? self : (gl==2)? vC : vB;
    float zraw = (gl==0)? vB   : (gl==1)? vC : (gl==2)? self : vA;
    float oraw = (gl==0)? vC   : (gl==1)? vB : (gl==2)? vA : self;
    float lfm = m + logsig_(fraw);
    float mnew = fmaxf(iraw, lfm);
    float ig = expneg_(iraw-mnew), fg=expneg_(lfm-mnew);
    c  = fg*c  + ig*tanh_(zraw);
    nn = fmaxf(fg*nn + ig, 1e-30f);
    float y = sig_(oraw) * c / nn;
    m = mnew;
    if (gl==0){ yS[wb][el]=y; ybuf[sl*64+el]=y; }
    __syncthreads();
    if (sl==YCH-1 || s==S_-1){
      int s0 = s-sl;
      int cnt = (sl+1)*64;
      for(int idx=tid; idx<cnt; idx+=256){
        int ss=s0+(idx>>6), ee=idx&63;
        y_out[((size_t)b*S_+ss)*256 + n*64 + ee] = ybuf[idx];
      }
      int nch=(s>>5)+1;
      if (nch<16){
        const float4* src=(const float4*)(wxBase+(size_t)nch*YCH*256);
        float4* dst=(float4*)&wxS[nch&1][0];
        #pragma unroll
        for(int j=0;j<8;j++) dst[j*256+tid]=src[j*256+tid];
      }
      __syncthreads();
    }
  }
}

// ---------------- yn-add + fused LN2 -> bf16 ----------------
__global__ __launch_bounds__(256) void k_ynadd_ln2(
  const float* __restrict__ y, const float* __restrict__ gn,
  float* __restrict__ x, const float* __restrict__ ln2w, bf16* __restrict__ h16)
{
  __shared__ float red[256];
  int r=blockIdx.x, t=threadIdx.x;
  float xv = x[(size_t)r*256+t];
  if (r < NROW){
    float v=y[(size_t)r*256+t];
    float s=v;
    for(int m=32;m;m>>=1) s+=__shfl_xor(s,m,64);
    float mu=s*(1.f/64.f);
    float d=v-mu;
    float q=d*d;
    for(int m=32;m;m>>=1) q+=__shfl_xor(q,m,64);
    float var=q*(1.f/64.f);
    xv += d*rsqrtf(var+EPS_)*gn[t];
    x[(size_t)r*256+t]=xv;
  }
  red[t]=xv; __syncthreads();
  for(int s=128;s>0;s>>=1){ if(t<s) red[t]+=red[t+s]; __syncthreads(); }
  float mu2=red[0]*(1.f/E_); __syncthreads();
  float dd=xv-mu2;
  red[t]=dd*dd; __syncthreads();
  for(int s=128;s>0;s>>=1){ if(t<s) red[t]+=red[t+s]; __syncthreads(); }
  float var2=red[0]*(1.f/E_);
  h16[(size_t)r*256+t]=__float2bfloat16(dd*rsqrtf(var2+EPS_)*ln2w[t]);
}

// ---------------- ffn gate: relu(gate)*upf -> bf16 ----------------
__global__ __launch_bounds__(256) void k_ffmul(const float* __restrict__ ffu, bf16* __restrict__ out)
{
  int i=blockIdx.x*256+threadIdx.x;
  int r=i/384, j=i%384;
  out[(size_t)r*384+j] = __float2bfloat16(fmaxf(ffu[(size_t)r*768+j],0.f)*ffu[(size_t)r*768+384+j]);
}

// ---------------- fused postnorm-LN + cq build -> bf16 ----------------
__global__ __launch_bounds__(256) void k_cq_ln(
  const float* __restrict__ x, const float* __restrict__ pw,
  const float* __restrict__ qe, const float* __restrict__ pide, const int* __restrict__ tgt,
  bf16* __restrict__ cq)
{
  __shared__ float red[256];
  int r=blockIdx.x, t=threadIdx.x;
  float v = x[(size_t)r*256+t];
  red[t]=v; __syncthreads();
  for(int s=128;s>0;s>>=1){ if(t<s) red[t]+=red[t+s]; __syncthreads(); }
  float mu=red[0]*(1.f/E_); __syncthreads();
  float d=v-mu;
  red[t]=d*d; __syncthreads();
  for(int s=128;s>0;s>>=1){ if(t<s) red[t]+=red[t+s]; __syncthreads(); }
  float var=red[0]*(1.f/E_);
  float dv = d*rsqrtf(var+EPS_)*pw[t];
  float pe=pide[r]; int tg=tgt[r];
  size_t base=(size_t)r*1024;
  cq[base+t]=__float2bfloat16(dv-pe);
  cq[base+256+t]=__float2bfloat16(qe[(size_t)r*256+t]);
  cq[base+512+t]=__float2bfloat16((tg==1)? dv:0.f);
  cq[base+768+t]=__float2bfloat16((tg==0)? dv:0.f);
}

// ---------------- final: selected logit + sigmoid ----------------
__global__ __launch_bounds__(256) void k_final(
  const float* __restrict__ o2, const float* __restrict__ w3, const float* __restrict__ b3,
  const int* __restrict__ qsh, float* __restrict__ out)
{
  __shared__ float red[256];
  int r=blockIdx.x, t=threadIdx.x;
  int qi=qsh[r];
  float p=o2[(size_t)r*256+t]*w3[(size_t)qi*256+t];
  red[t]=p; __syncthreads();
  for(int s=128;s>0;s>>=1){ if(t<s) red[t]+=red[t+s]; __syncthreads(); }
  if(t==0) out[r]=sig_(red[0]+b3[qi]);
}

// ---------------- launch ----------------
extern "C" void kernel_launch(void* const* d_in, const int* in_sizes, int n_in,
                              void* d_out, int out_size, void* d_ws, size_t ws_size,
                              hipStream_t stream) {
  const int* questions = (const int*)d_in[0];
  const int* responses = (const int*)d_in[1];
  const int* skills    = (const int*)d_in[2];
  const float* q_embed       = (const float*)d_in[4];
  const float* qa_embed      = (const float*)d_in[5];
  const float* q_embed_diff  = (const float*)d_in[6];
  const float* qa_embed_diff = (const float*)d_in[7];
  const float* difficult_param=(const float*)d_in[8];
  const float* ln0_w   = (const float*)d_in[9];
  const float* m_up_w  = (const float*)d_in[10];
  const float* m_up_b  = (const float*)d_in[11];
  const float* m_conv_w= (const float*)d_in[12];
  const float* m_conv_b= (const float*)d_in[13];
  const float* m_q_w   = (const float*)d_in[14];
  const float* m_k_w   = (const float*)d_in[15];
  const float* m_v_w   = (const float*)d_in[16];
  const float* m_ig_w  = (const float*)d_in[17];
  const float* m_ig_b  = (const float*)d_in[18];
  const float* m_fg_w  = (const float*)d_in[19];
  const float* m_fg_b  = (const float*)d_in[20];
  const float* m_outnorm_w=(const float*)d_in[21];
  const float* m_skip  = (const float*)d_in[22];
  const float* m_down_w= (const float*)d_in[23];
  const float* m_down_b= (const float*)d_in[24];
  const float* ln1_w   = (const float*)d_in[25];
  const float* s_conv_w= (const float*)d_in[26];
  const float* s_conv_b= (const float*)d_in[27];
  const float* s_gate_w= (const float*)d_in[28];
  const float* s_rec_w = (const float*)d_in[29];
  const float* s_bias  = (const float*)d_in[30];
  const float* s_gn_w  = (const float*)d_in[31];
  const float* ln2_w   = (const float*)d_in[32];
  const float* ffn_up_w= (const float*)d_in[33];
  const float* ffn_up_b= (const float*)d_in[34];
  const float* ffn_down_w=(const float*)d_in[35];
  const float* ffn_down_b=(const float*)d_in[36];
  const float* postnorm_w=(const float*)d_in[37];
  const float* out_w1  = (const float*)d_in[38];
  const float* out_b1  = (const float*)d_in[39];
  const float* out_w2  = (const float*)d_in[40];
  const float* out_b2  = (const float*)d_in[41];
  const float* out_w3  = (const float*)d_in[42];
  const float* out_b3  = (const float*)d_in[43];

  float* ws = (float*)d_ws;
  const size_t R = (size_t)NP_*256;
  float* x    = ws;
  float* qe   = ws + R;
  float* h    = ws + 2*R;
  float* t256 = ws + 3*R;
  float* A    = ws + 4*R;        // NP x 1024 ; also scan-layout wx
  float* Bb   = ws + 8*R;        // NP x 512
  float* Cb   = ws + 10*R;       // NP x 512  (q; later y_out; later b16)
  float* Db   = ws + 12*R;       // NP x 512  (k; later hout16 / ffg16)
  float* Eb   = ws + 14*R;       // NP x 512  (v; later cq16)
  float* pide = ws + 16*R;
  int*   tgt  = (int*)(ws + 16*R + NP_);
  int*   qsh  = (int*)(ws + 16*R + 2*NP_);
  float* igb  = ws + 16*R + 3*NP_;
  float* fgb  = igb + 64*512;
  float* cs1  = fgb + 64*512;
  float* gdec = cs1 + 64*512;
  float* Mrun = gdec + 64*512;
  bf16* wpool = (bf16*)(Mrun + 64*512);
  bf16* m_down_w16  = wpool;
  bf16* ffn_up_w16  = m_down_w16 + 256*512;
  bf16* ffn_down_w16= ffn_up_w16 + 768*256;
  bf16* out_w1_16   = ffn_down_w16 + 256*384;
  bf16* out_w2_16   = out_w1_16 + 512*1024;
  bf16* h16         = out_w2_16 + 256*512;
  bf16* hout16 = (bf16*)Db;
  bf16* ffg16  = (bf16*)Db;
  bf16* cq16   = (bf16*)Eb;
  bf16* b16    = (bf16*)Cb;

  // ---- one-time weight conversions ----
  k_cvt16<<<(256*512+255)/256,256,0,stream>>>(m_down_w,  m_down_w16,  256*512);
  k_cvt16<<<(768*256+255)/256,256,0,stream>>>(ffn_up_w,  ffn_up_w16,  768*256);
  k_cvt16<<<(256*384+255)/256,256,0,stream>>>(ffn_down_w,ffn_down_w16,256*384);
  k_cvt16<<<(512*1024+255)/256,256,0,stream>>>(out_w1,   out_w1_16,   512*1024);
  k_cvt16<<<(256*512+255)/256,256,0,stream>>>(out_w2,    out_w2_16,   256*512);

  // ---- embeddings (+LN0) ----
  k_embed<<<NP_,256,0,stream>>>(questions,responses,skills,q_embed,qa_embed,
      q_embed_diff,qa_embed_diff,difficult_param, ln0_w, x,qe,h, pide,tgt,qsh);
  // ---- block M ----
  k_gemm<<<dim3(1024/64,NP_/64),256,0,stream>>>(h,256, m_up_w, m_up_b, A, 1024,256,0);
  k_conv_silu<<<(NP_*512)/256,256,0,stream>>>(A,1024, m_conv_w,m_conv_b, Bb,512,512);
  k_headwise<<<(NP_*512)/256,256,0,stream>>>(Bb, A,1024, m_q_w,m_k_w,m_v_w, Cb,Db,Eb);
  k_igfg<<<NROW,256,0,stream>>>(Cb,Db,Eb, m_ig_w,m_ig_b,m_fg_w,m_fg_b, igb,fgb);
  k_decay<<<64,256,0,stream>>>(igb,fgb, cs1,gdec,Mrun);
  k_attn<<<dim3((S_+TQ-1)/TQ, B_*NH_),256,0,stream>>>(Cb,Db,Eb, cs1,gdec,Mrun, m_outnorm_w, A);
  k_hout<<<(NP_*512)/256,256,0,stream>>>(A, Bb, m_skip, hout16);
  k_gemm16<<<dim3(256/64,NP_/64),256,0,stream>>>(hout16, m_down_w16, m_down_b, x, x, (bf16*)nullptr, 256,512,0);
  // ---- block S ----
  k_ln<<<NP_,256,0,stream>>>(x, ln1_w, h);
  k_conv_silu<<<(NP_*256)/256,256,0,stream>>>(h,256, s_conv_w,s_conv_b, Bb,256,256);
  k_wx<<<NROW,256,0,stream>>>(h, Bb, s_gate_w, s_bias, A);
  k_scan<<<64,256,0,stream>>>(A, s_rec_w, Cb);
  k_ynadd_ln2<<<NP_,256,0,stream>>>(Cb, s_gn_w, x, ln2_w, h16);
  // ---- FFN ----
  k_gemm16<<<dim3(768/64,NP_/64),256,0,stream>>>(h16, ffn_up_w16, ffn_up_b, (const float*)nullptr, A, (bf16*)nullptr, 768,256,0);
  k_ffmul<<<(NP_*384)/256,256,0,stream>>>(A, ffg16);
  k_gemm16<<<dim3(256/64,NP_/64),256,0,stream>>>(ffg16, ffn_down_w16, ffn_down_b, x, x, (bf16*)nullptr, 256,384,0);
  // ---- output head ----
  k_cq_ln<<<NP_,256,0,stream>>>(x, postnorm_w, qe, pide, tgt, cq16);
  k_gemm16<<<dim3(512/64,NP_/64),256,0,stream>>>(cq16, out_w1_16, out_b1, (const float*)nullptr, (float*)nullptr, b16, 512,1024,1);
  k_gemm16<<<dim3(256/64,NP_/64),256,0,stream>>>(b16, out_w2_16, out_b2, (const float*)nullptr, t256, (bf16*)nullptr, 256,512,1);
  k_final<<<NROW,256,0,stream>>>(t256, out_w3, out_b3, qsh, (float*)d_out);
}

// Round 10
// 1470.782 us; speedup vs baseline: 1.0571x; 1.0571x over previous
//
#include <hip/hip_runtime.h>
#include <hip/hip_bf16.h>

// ---------------- constants ----------------
#define B_    16
#define SL_   512
#define S_    511
#define E_    256
#define NH_   4
#define I_    512
#define DHM_  128
#define DHS_  64
#define F_    384
#define NP_   8192               // padded row count (multiple of 64)
#define NROW  (B_*S_)            // 8176 real rows
#define EPS_  1e-5f

typedef __hip_bfloat16 bf16;
typedef __bf16 bf16x8v __attribute__((ext_vector_type(8)));
typedef float  f32x4v  __attribute__((ext_vector_type(4)));

__device__ __forceinline__ float sig_(float x){ return 1.f/(1.f+__expf(-x)); }
__device__ __forceinline__ float silu_(float x){ return x*sig_(x); }
__device__ __forceinline__ float logsig_(float x){ return fminf(x,0.f) - log1pf(__expf(-fabsf(x))); }
__device__ __forceinline__ float expneg_(float x){ return __expf(fminf(x,0.f)); }
__device__ __forceinline__ float expclamp_(float x){ return __expf(fminf(fmaxf(x,-80.f),80.f)); }
__device__ __forceinline__ float tanh_(float x){ return 1.f - 2.f/(__expf(2.f*x)+1.f); }
__device__ __forceinline__ float rdlane_(float v, int l){
  return __uint_as_float(__builtin_amdgcn_readlane(__float_as_uint(v), (unsigned)l));
}

// ---------------- f32 -> bf16 weight conversion ----------------
__global__ __launch_bounds__(256) void k_cvt16(const float* __restrict__ src, bf16* __restrict__ dst, int n){
  int i=blockIdx.x*256+threadIdx.x;
  if(i<n) dst[i]=__float2bfloat16(src[i]);
}

// ---------------- embedding gather + fused LN0 ----------------
__global__ __launch_bounds__(256) void k_embed(
  const int* __restrict__ questions, const int* __restrict__ responses, const int* __restrict__ skills,
  const float* __restrict__ q_embed, const float* __restrict__ qa_embed,
  const float* __restrict__ q_embed_diff, const float* __restrict__ qa_embed_diff,
  const float* __restrict__ difficult_param, const float* __restrict__ ln0w,
  float* __restrict__ x, float* __restrict__ qe, float* __restrict__ h,
  float* __restrict__ pide, int* __restrict__ tgt, int* __restrict__ qsh)
{
  __shared__ float red[256];
  int r = blockIdx.x; int e = threadIdx.x;
  float xa = 0.f;
  if (r < NROW){
    int b = r / S_, s = r % S_;
    int pid  = questions[b*SL_+s];
    int qd   = skills[b*SL_+s];
    int resp = responses[b*SL_+s];
    int t    = (resp > -1) ? resp : 0;
    float pe = difficult_param[pid];
    float q0 = q_embed[qd*E_+e];
    xa = q0 + qa_embed[t*E_+e] + pe*qa_embed_diff[t*E_+e];
    float qn = q0 + pe*q_embed_diff[qd*E_+e];
    x[(size_t)r*E_+e]=xa; qe[(size_t)r*E_+e]=qn;
    if (e==0){ pide[r]=pe; tgt[r]=t; qsh[r]=skills[b*SL_+s+1]; }
  } else {
    x[(size_t)r*E_+e]=0.f; qe[(size_t)r*E_+e]=0.f;
    if (e==0){ pide[r]=0.f; tgt[r]=-7; qsh[r]=0; }
  }
  red[e]=xa; __syncthreads();
  for(int s2=128;s2>0;s2>>=1){ if(e<s2) red[e]+=red[e+s2]; __syncthreads(); }
  float mu = red[0]*(1.f/E_); __syncthreads();
  float d = xa-mu;
  red[e]=d*d; __syncthreads();
  for(int s2=128;s2>0;s2>>=1){ if(e<s2) red[e]+=red[e+s2]; __syncthreads(); }
  float var = red[0]*(1.f/E_);
  h[(size_t)r*E_+e] = d*rsqrtf(var+EPS_)*ln0w[e];
}

// ---------------- layernorm over E=256 (used for ln1) ----------------
__global__ __launch_bounds__(256) void k_ln(
  const float* __restrict__ in, const float* __restrict__ w, float* __restrict__ out)
{
  __shared__ float red[256];
  int r = blockIdx.x, t = threadIdx.x;
  float v = in[(size_t)r*E_+t];
  red[t]=v; __syncthreads();
  for(int s=128;s>0;s>>=1){ if(t<s) red[t]+=red[t+s]; __syncthreads(); }
  float mu = red[0]*(1.f/E_); __syncthreads();
  float d = v-mu;
  red[t]=d*d; __syncthreads();
  for(int s=128;s>0;s>>=1){ if(t<s) red[t]+=red[t+s]; __syncthreads(); }
  float var = red[0]*(1.f/E_);
  out[(size_t)r*E_+t] = d*rsqrtf(var+EPS_)*w[t];
}

// ---------------- f32 GEMM (kept for m_up only) ----------------
__global__ __launch_bounds__(256) void k_gemm(
  const float* __restrict__ A, int lda,
  const float* __restrict__ Bw, const float* __restrict__ bias,
  float* __restrict__ C, int M, int K, int relu)
{
  __shared__ __align__(16) float As[16][68];
  __shared__ __align__(16) float Bs[16][68];
  int tid = threadIdx.x;
  int row0 = blockIdx.y*64, col0 = blockIdx.x*64;
  int tm=(tid/16)*4, tn=(tid%16)*4;
  int lk=tid%16, lm=tid/16;
  float acc[4][4]={};
  for(int k0=0;k0<K;k0+=16){
    #pragma unroll
    for(int i=0;i<4;i++){
      int m=lm+i*16;
      As[lk][m]=A[(size_t)(row0+m)*lda + k0+lk];
      Bs[lk][m]=Bw[(size_t)(col0+m)*K + k0+lk];
    }
    __syncthreads();
    #pragma unroll
    for(int k=0;k<16;k++){
      float4 a=*(const float4*)&As[k][tm];
      float4 b=*(const float4*)&Bs[k][tn];
      float av[4]={a.x,a.y,a.z,a.w};
      float bv[4]={b.x,b.y,b.z,b.w};
      #pragma unroll
      for(int i=0;i<4;i++)
        #pragma unroll
        for(int j=0;j<4;j++) acc[i][j]+=av[i]*bv[j];
    }
    __syncthreads();
  }
  #pragma unroll
  for(int i=0;i<4;i++){
    #pragma unroll
    for(int j=0;j<4;j++){
      float v=acc[i][j] + (bias? bias[col0+tn+j] : 0.f);
      if(relu) v=fmaxf(v,0.f);
      C[(size_t)(row0+tm+i)*M + col0+tn+j]=v;
    }
  }
}

// ---------------- bf16 MFMA GEMM (+ optional residual) ----------------
__global__ __launch_bounds__(256) void k_gemm16(
  const bf16* __restrict__ A, const bf16* __restrict__ Bw,
  const float* __restrict__ bias, const float* __restrict__ resid,
  float* __restrict__ C, bf16* __restrict__ C16,
  int M, int K, int relu)
{
  int tid=threadIdx.x;
  int wave=tid>>6, lane=tid&63;
  int wr=wave>>1, wc=wave&1;
  int row0=blockIdx.y*64 + wr*32;
  int col0=blockIdx.x*64 + wc*32;
  int lrow = lane&15, lq = lane>>4;
  f32x4v acc[2][2] = {};
  const bf16* Abase = A  + (size_t)(row0+lrow)*K + lq*8;
  const bf16* Bbase = Bw + (size_t)(col0+lrow)*K + lq*8;
  for(int k0=0;k0<K;k0+=32){
    bf16x8v a0 = *(const bf16x8v*)(Abase + k0);
    bf16x8v a1 = *(const bf16x8v*)(Abase + (size_t)16*K + k0);
    bf16x8v b0 = *(const bf16x8v*)(Bbase + k0);
    bf16x8v b1 = *(const bf16x8v*)(Bbase + (size_t)16*K + k0);
    acc[0][0]=__builtin_amdgcn_mfma_f32_16x16x32_bf16(a0,b0,acc[0][0],0,0,0);
    acc[0][1]=__builtin_amdgcn_mfma_f32_16x16x32_bf16(a0,b1,acc[0][1],0,0,0);
    acc[1][0]=__builtin_amdgcn_mfma_f32_16x16x32_bf16(a1,b0,acc[1][0],0,0,0);
    acc[1][1]=__builtin_amdgcn_mfma_f32_16x16x32_bf16(a1,b1,acc[1][1],0,0,0);
  }
  #pragma unroll
  for(int mi=0;mi<2;mi++){
    #pragma unroll
    for(int ni=0;ni<2;ni++){
      #pragma unroll
      for(int r=0;r<4;r++){
        int row=row0+mi*16+lq*4+r;       // C/D: col=lane&15, row=(lane>>4)*4+reg  [m89]
        int col=col0+ni*16+lrow;
        float v=acc[mi][ni][r] + (bias? bias[col]:0.f);
        if(relu) v=fmaxf(v,0.f);
        if(resid) v += resid[(size_t)row*M+col];
        if(C)   C[(size_t)row*M+col]=v;
        if(C16) C16[(size_t)row*M+col]=__float2bfloat16(v);
      }
    }
  }
}

// ---------------- causal depthwise conv K=4 + silu ----------------
__global__ __launch_bounds__(256) void k_conv_silu(
  const float* __restrict__ in, int ild, const float* __restrict__ w, const float* __restrict__ bws,
  float* __restrict__ out, int old_, int C)
{
  int i = blockIdx.x*256 + threadIdx.x;
  int r = i / C, c = i % C;
  if (r >= NP_) return;
  float acc = 0.f;
  if (r < NROW) {
    int b=r/S_, s=r%S_;
    acc = bws[c];
    #pragma unroll
    for(int j=0;j<4;j++){
      int ss=s-3+j;
      if(ss>=0) acc += w[c*4+j] * in[(size_t)(b*S_+ss)*ild + c];
    }
    acc = silu_(acc);
  }
  out[(size_t)r*old_ + c] = acc;
}

// ---------------- headwise 4x4 block projections q,k,v ----------------
__global__ __launch_bounds__(256) void k_headwise(
  const float* __restrict__ xc, const float* __restrict__ xm, int xmld,
  const float* __restrict__ wq, const float* __restrict__ wk, const float* __restrict__ wv,
  float* __restrict__ q, float* __restrict__ k, float* __restrict__ v)
{
  int i=blockIdx.x*256+threadIdx.x;
  int r=i/I_, c=i%I_;
  if(r>=NP_) return;
  size_t oi=(size_t)r*I_+c;
  if(r>=NROW){ q[oi]=0.f; k[oi]=0.f; v[oi]=0.f; return; }
  int n=c>>2, o=c&3;
  const float* xcr = xc + (size_t)r*I_ + n*4;
  const float* xmr = xm + (size_t)r*xmld + n*4;
  float aq=0.f, ak=0.f, av=0.f;
  #pragma unroll
  for(int d=0;d<4;d++){
    float xcv=xcr[d], xmv=xmr[d];
    aq += xcv*wq[(n*4+o)*4+d];
    ak += xcv*wk[(n*4+o)*4+d];
    av += xmv*wv[(n*4+o)*4+d];
  }
  q[oi]=aq; k[oi]=ak; v[oi]=av;
}

// ---------------- ig/fg gates ----------------
__global__ __launch_bounds__(256) void k_igfg(
  const float* __restrict__ q, const float* __restrict__ k, const float* __restrict__ v,
  const float* __restrict__ wig, const float* __restrict__ big,
  const float* __restrict__ wfg, const float* __restrict__ bfg,
  float* __restrict__ igb, float* __restrict__ fgb)
{
  int r=blockIdx.x;
  int wid=threadIdx.x>>6, lane=threadIdx.x&63;
  int b=r/S_, s=r%S_;
  for(int c=wid; c<8; c+=4){
    int h=c>>1; int isfg=c&1;
    const float* w = isfg? wfg : wig;
    float acc=0.f;
    for(int f=lane; f<1536; f+=64){
      float val = (f<512)? q[(size_t)r*512+f]
                : (f<1024)? k[(size_t)r*512+f-512]
                : v[(size_t)r*512+f-1024];
      acc += val*w[h*1536+f];
    }
    for(int m=32;m;m>>=1) acc+=__shfl_xor(acc,m,64);
    if(lane==0){
      if(isfg) fgb[(b*4+h)*512+s]=acc+bfg[h];
      else     igb[(b*4+h)*512+s]=acc+big[h];
    }
  }
}

// ---------------- decay prep (parallel scans): one block per bh ----------------
__global__ __launch_bounds__(256) void k_decay(
  const float* __restrict__ igb, const float* __restrict__ fgb,
  float* __restrict__ cs1, float* __restrict__ g, float* __restrict__ M)
{
  int bh = blockIdx.x; int tid = threadIdx.x;
  __shared__ float buf[512];
  __shared__ float buf2[512];
  for (int s=tid; s<512; s+=256)
    buf[s] = (s<S_) ? logsig_(fgb[bh*512+s]) : 0.f;
  __syncthreads();
  for (int off=1; off<512; off<<=1){
    int s0=tid, s1=tid+256;
    float v0 = buf[s0] + ((s0>=off)? buf[s0-off] : 0.f);
    float v1 = buf[s1] + ((s1>=off)? buf[s1-off] : 0.f);
    __syncthreads();
    buf[s0]=v0; buf[s1]=v1;
    __syncthreads();
  }
  for (int s=tid; s<512; s+=256){
    float c = buf[s];
    if (s<S_){
      cs1[bh*512+s]=c;
      float gv = igb[bh*512+s]-c;
      g[bh*512+s]=gv;
      buf2[s]=gv;
    } else buf2[s] = -3.4e38f;
  }
  __syncthreads();
  for (int off=1; off<512; off<<=1){
    int s0=tid, s1=tid+256;
    float v0 = fmaxf(buf2[s0], (s0>=off)? buf2[s0-off] : -3.4e38f);
    float v1 = fmaxf(buf2[s1], (s1>=off)? buf2[s1-off] : -3.4e38f);
    __syncthreads();
    buf2[s0]=v0; buf2[s1]=v1;
    __syncthreads();
  }
  for (int s=tid; s<S_; s+=256) M[bh*512+s] = buf2[s];
}

// ---------------- tiled attention (unchanged) ----------------
#define TQ 32
#define TS 32
__global__ __launch_bounds__(256) void k_attn(
  const float* __restrict__ q, const float* __restrict__ k, const float* __restrict__ v,
  const float* __restrict__ cs1, const float* __restrict__ g, const float* __restrict__ M,
  const float* __restrict__ onw, float* __restrict__ hflat)
{
  __shared__ __align__(16) float qs[TQ][132];
  __shared__ __align__(16) float ks[TS][132];
  __shared__ __align__(16) float vs[TS][128];
  __shared__ float Sw[TQ][33];
  __shared__ float MtS[TQ], cssS[TQ], lsumS[TQ], gsS[TS];
  int tq = blockIdx.x, bh = blockIdx.y;
  int b = bh>>2, h = bh&3;
  int tid = threadIdx.x;
  int i = tid>>4, j = tid&15;
  int t0 = tq*TQ;
  {
    int row = tid>>3, c4 = (tid&7)*4;
    const float4* src = (const float4*)(q + (size_t)(b*S_ + t0 + row)*512 + h*128);
    float4* dst = (float4*)&qs[row][0];
    #pragma unroll
    for(int c=0;c<4;c++) dst[c4+c] = src[c4+c];
  }
  if (tid < TQ){
    int t = t0 + tid; int tc = (t<S_)? t : (S_-1);
    MtS[tid]  = M[bh*512 + tc];
    cssS[tid] = cs1[bh*512 + tc];
    lsumS[tid]= 0.f;
  }
  float o[2][8] = {};
  int t1 = min(t0+TQ, S_);
  int nst = (t1 + TS - 1)/TS;
  const float sc = 0.08838834764831843f;
  for (int st=0; st<nst; ++st){
    int s0 = st*TS;
    __syncthreads();
    {
      int row = tid>>3, c4 = (tid&7)*4;
      const float4* srck = (const float4*)(k + (size_t)(b*S_ + s0 + row)*512 + h*128);
      const float4* srcv = (const float4*)(v + (size_t)(b*S_ + s0 + row)*512 + h*128);
      float4* dk = (float4*)&ks[row][0];
      float4* dv = (float4*)&vs[row][0];
      #pragma unroll
      for(int c=0;c<4;c++){ dk[c4+c]=srck[c4+c]; dv[c4+c]=srcv[c4+c]; }
      if (tid < TS) gsS[tid] = g[bh*512 + s0 + tid];
    }
    __syncthreads();
    float a00=0,a01=0,a10=0,a11=0;
    {
      const float4* q0 = (const float4*)&qs[i*2][0];
      const float4* q1 = (const float4*)&qs[i*2+1][0];
      const float4* k0 = (const float4*)&ks[j][0];
      const float4* k1 = (const float4*)&ks[j+16][0];
      #pragma unroll
      for(int d4=0; d4<32; ++d4){
        float4 qa=q0[d4], qb=q1[d4], ka=k0[d4], kb=k1[d4];
        a00 += qa.x*ka.x+qa.y*ka.y+qa.z*ka.z+qa.w*ka.w;
        a01 += qa.x*kb.x+qa.y*kb.y+qa.z*kb.z+qa.w*kb.w;
        a10 += qb.x*ka.x+qb.y*ka.y+qb.z*ka.z+qb.w*ka.w;
        a11 += qb.x*kb.x+qb.y*kb.y+qb.z*kb.z+qb.w*kb.w;
      }
    }
    int tA = t0 + i*2, tB = tA+1;
    int sA = s0 + j,   sB = sA + 16;
    float gA = gsS[j], gB = gsS[j+16];
    float mA = MtS[i*2], mB = MtS[i*2+1];
    float w00 = (sA<=tA)? a00*sc*expneg_(gA-mA) : 0.f;
    float w01 = (sB<=tA)? a01*sc*expneg_(gB-mA) : 0.f;
    float w10 = (sA<=tB)? a10*sc*expneg_(gA-mB) : 0.f;
    float w11 = (sB<=tB)? a11*sc*expneg_(gB-mB) : 0.f;
    float r0 = w00+w01, r1 = w10+w11;
    #pragma unroll
    for(int msk=1; msk<16; msk<<=1){ r0 += __shfl_xor(r0,msk,16); r1 += __shfl_xor(r1,msk,16); }
    if (j==0){ lsumS[i*2] += r0; lsumS[i*2+1] += r1; }
    Sw[i*2][j]     = w00; Sw[i*2][j+16]   = w01;
    Sw[i*2+1][j]   = w10; Sw[i*2+1][j+16] = w11;
    __syncthreads();
    #pragma unroll 8
    for(int s=0;s<TS;s++){
      float w0 = Sw[i*2][s], w1 = Sw[i*2+1][s];
      float4 v0 = *(const float4*)&vs[s][j*4];
      float4 v1 = *(const float4*)&vs[s][64+j*4];
      o[0][0]+=w0*v0.x; o[0][1]+=w0*v0.y; o[0][2]+=w0*v0.z; o[0][3]+=w0*v0.w;
      o[0][4]+=w0*v1.x; o[0][5]+=w0*v1.y; o[0][6]+=w0*v1.z; o[0][7]+=w0*v1.w;
      o[1][0]+=w1*v0.x; o[1][1]+=w1*v0.y; o[1][2]+=w1*v0.z; o[1][3]+=w1*v0.w;
      o[1][4]+=w1*v1.x; o[1][5]+=w1*v1.y; o[1][6]+=w1*v1.z; o[1][7]+=w1*v1.w;
    }
  }
  __syncthreads();
  #pragma unroll
  for(int r=0;r<2;r++){
    int tl = i*2+r;
    int t = t0 + tl;
    float maxD = cssS[tl] + MtS[tl];
    float norm = fmaxf(fabsf(lsumS[tl]), expclamp_(-maxD));
    float scale = 1.f/(norm+1e-6f);
    float sum=0.f;
    #pragma unroll
    for(int d=0;d<8;d++){ o[r][d]*=scale; sum+=o[r][d]; }
    #pragma unroll
    for(int msk=1; msk<16; msk<<=1) sum += __shfl_xor(sum,msk,16);
    float mu = sum*(1.f/128.f);
    float var=0.f;
    #pragma unroll
    for(int d=0;d<8;d++){ float dd=o[r][d]-mu; var+=dd*dd; }
    #pragma unroll
    for(int msk=1; msk<16; msk<<=1) var += __shfl_xor(var,msk,16);
    float rs = rsqrtf(var*(1.f/128.f)+EPS_);
    if (t < S_){
      float* dst = hflat + (size_t)(b*S_+t)*1024 + h*128;
      #pragma unroll
      for(int c=0;c<4;c++) dst[j*4+c]    = (o[r][c]  -mu)*rs*onw[h*128+j*4+c];
      #pragma unroll
      for(int c=0;c<4;c++) dst[64+j*4+c] = (o[r][4+c]-mu)*rs*onw[h*128+64+j*4+c];
    }
  }
}

// ---------------- hout = (hflat + skip*xc) * silu(z) -> bf16 ----------------
__global__ __launch_bounds__(256) void k_hout(
  const float* __restrict__ A, const float* __restrict__ xc, const float* __restrict__ skip,
  bf16* __restrict__ out16)
{
  int i=blockIdx.x*256+threadIdx.x;
  int r=i/512, c=i%512;
  float hf=A[(size_t)r*1024+c];
  float z =A[(size_t)r*1024+512+c];
  out16[(size_t)r*512+c] = __float2bfloat16((hf + skip[c]*xc[(size_t)r*512+c]) * silu_(z));
}

// ---------------- wx = gate pre-activations, scan layout [bn][s][g*64+e] ----------------
__global__ __launch_bounds__(256) void k_wx(
  const float* __restrict__ h, const float* __restrict__ hc,
  const float* __restrict__ gw, const float* __restrict__ gb,
  float* __restrict__ wx)
{
  __shared__ float hs[256], hcs[256];
  int r=blockIdx.x; int t=threadIdx.x;
  hs[t]=h[(size_t)r*256+t]; hcs[t]=hc[(size_t)r*256+t];
  __syncthreads();
  int b=r/S_, s=r%S_;
  int n=t>>6, e=t&63;
  #pragma unroll
  for(int gg=0; gg<4; gg++){
    const float* src = (gg<2? hcs: hs) + n*64;
    const float* wp = gw + (size_t)(((gg*4+n)*64+e))*64;
    float acc=gb[(gg*4+n)*64+e];
    #pragma unroll 8
    for(int d=0;d<64;d++) acc+=src[d]*wp[d];
    wx[((size_t)(b*4+n)*512 + s)*256 + gg*64 + e]=acc;
  }
}

// ---------------- sLSTM scan: y in registers, readlane matvec, 1 barrier/step ----------------
// Wave g computes gate g's matvec from its own replicated yreg (lane e holds y[e]):
//   a = wx + sum_d readlane(yreg,d)*W[d]   -- zero LDS traffic for y.
// Gate exchange via ping-pong rawS (b32); gate chain replicated in all 4 waves so each
// wave updates yreg locally. y_out: fire-and-forget store by wave 0.
#define YCH 32
__global__ __launch_bounds__(256,1) void k_scan(
  const float* __restrict__ wx, const float* __restrict__ rw, float* __restrict__ y_out)
{
  int bn = blockIdx.x; int b = bn>>2, n = bn&3;
  int tid = threadIdx.x; int g = tid>>6, e = tid&63;
  float W[64];
  #pragma unroll
  for(int d=0;d<64;d++) W[d]=rw[(size_t)(((g*4+n)*64+d))*64 + e];
  __shared__ float rawS[2][256];
  __shared__ __align__(16) float wxS[2][YCH*256];
  const float* wxBase = wx + (size_t)bn*512*256;
  { // stage chunk 0
    const float4* src=(const float4*)wxBase;
    float4* dst=(float4*)&wxS[0][0];
    #pragma unroll
    for(int j=0;j<8;j++) dst[j*256+tid]=src[j*256+tid];
  }
  float c=0.f, nn=0.f, m=0.f, yreg=0.f;
  __syncthreads();
  for (int s=0; s<S_; ++s){
    int sl = s & (YCH-1);
    int p  = s & 1;
    if (sl == 0){
      int nch=(s>>5)+1;
      if (nch<16){
        const float4* src=(const float4*)(wxBase+(size_t)nch*YCH*256);
        float4* dst=(float4*)&wxS[nch&1][0];
        #pragma unroll
        for(int j=0;j<8;j++) dst[j*256+tid]=src[j*256+tid];
      }
    }
    float wxv = wxS[(s>>5)&1][sl*256 + tid];
    float a0=0.f,a1=0.f,a2=0.f,a3=0.f;
    #pragma unroll
    for(int d=0; d<64; d+=4){
      a0 += rdlane_(yreg,d  )*W[d  ];
      a1 += rdlane_(yreg,d+1)*W[d+1];
      a2 += rdlane_(yreg,d+2)*W[d+2];
      a3 += rdlane_(yreg,d+3)*W[d+3];
    }
    rawS[p][tid] = wxv + ((a0+a1)+(a2+a3));
    __syncthreads();
    float iraw=rawS[p][e], fraw=rawS[p][64+e], zraw=rawS[p][128+e], oraw=rawS[p][192+e];
    float lfm = m + logsig_(fraw);
    float mnew = fmaxf(iraw, lfm);
    float ig = expneg_(iraw-mnew), fg=expneg_(lfm-mnew);
    c  = fg*c  + ig*tanh_(zraw);
    nn = fmaxf(fg*nn + ig, 1e-30f);
    float y = sig_(oraw) * c / nn;
    m = mnew;
    yreg = y;
    if (g==0) y_out[((size_t)b*S_+s)*256 + n*64 + e] = y;
  }
}

// ---------------- yn-add + fused LN2 -> bf16 ----------------
__global__ __launch_bounds__(256) void k_ynadd_ln2(
  const float* __restrict__ y, const float* __restrict__ gn,
  float* __restrict__ x, const float* __restrict__ ln2w, bf16* __restrict__ h16)
{
  __shared__ float red[256];
  int r=blockIdx.x, t=threadIdx.x;
  float xv = x[(size_t)r*256+t];
  if (r < NROW){
    float v=y[(size_t)r*256+t];
    float s=v;
    for(int m=32;m;m>>=1) s+=__shfl_xor(s,m,64);
    float mu=s*(1.f/64.f);
    float d=v-mu;
    float q=d*d;
    for(int m=32;m;m>>=1) q+=__shfl_xor(q,m,64);
    float var=q*(1.f/64.f);
    xv += d*rsqrtf(var+EPS_)*gn[t];
    x[(size_t)r*256+t]=xv;
  }
  red[t]=xv; __syncthreads();
  for(int s=128;s>0;s>>=1){ if(t<s) red[t]+=red[t+s]; __syncthreads(); }
  float mu2=red[0]*(1.f/E_); __syncthreads();
  float dd=xv-mu2;
  red[t]=dd*dd; __syncthreads();
  for(int s=128;s>0;s>>=1){ if(t<s) red[t]+=red[t+s]; __syncthreads(); }
  float var2=red[0]*(1.f/E_);
  h16[(size_t)r*256+t]=__float2bfloat16(dd*rsqrtf(var2+EPS_)*ln2w[t]);
}

// ---------------- ffn gate: relu(gate)*upf -> bf16 ----------------
__global__ __launch_bounds__(256) void k_ffmul(const float* __restrict__ ffu, bf16* __restrict__ out)
{
  int i=blockIdx.x*256+threadIdx.x;
  int r=i/384, j=i%384;
  out[(size_t)r*384+j] = __float2bfloat16(fmaxf(ffu[(size_t)r*768+j],0.f)*ffu[(size_t)r*768+384+j]);
}

// ---------------- fused postnorm-LN + cq build -> bf16 ----------------
__global__ __launch_bounds__(256) void k_cq_ln(
  const float* __restrict__ x, const float* __restrict__ pw,
  const float* __restrict__ qe, const float* __restrict__ pide, const int* __restrict__ tgt,
  bf16* __restrict__ cq)
{
  __shared__ float red[256];
  int r=blockIdx.x, t=threadIdx.x;
  float v = x[(size_t)r*256+t];
  red[t]=v; __syncthreads();
  for(int s=128;s>0;s>>=1){ if(t<s) red[t]+=red[t+s]; __syncthreads(); }
  float mu=red[0]*(1.f/E_); __syncthreads();
  float d=v-mu;
  red[t]=d*d; __syncthreads();
  for(int s=128;s>0;s>>=1){ if(t<s) red[t]+=red[t+s]; __syncthreads(); }
  float var=red[0]*(1.f/E_);
  float dv = d*rsqrtf(var+EPS_)*pw[t];
  float pe=pide[r]; int tg=tgt[r];
  size_t base=(size_t)r*1024;
  cq[base+t]=__float2bfloat16(dv-pe);
  cq[base+256+t]=__float2bfloat16(qe[(size_t)r*256+t]);
  cq[base+512+t]=__float2bfloat16((tg==1)? dv:0.f);
  cq[base+768+t]=__float2bfloat16((tg==0)? dv:0.f);
}

// ---------------- final: selected logit + sigmoid ----------------
__global__ __launch_bounds__(256) void k_final(
  const float* __restrict__ o2, const float* __restrict__ w3, const float* __restrict__ b3,
  const int* __restrict__ qsh, float* __restrict__ out)
{
  __shared__ float red[256];
  int r=blockIdx.x, t=threadIdx.x;
  int qi=qsh[r];
  float p=o2[(size_t)r*256+t]*w3[(size_t)qi*256+t];
  red[t]=p; __syncthreads();
  for(int s=128;s>0;s>>=1){ if(t<s) red[t]+=red[t+s]; __syncthreads(); }
  if(t==0) out[r]=sig_(red[0]+b3[qi]);
}

// ---------------- launch ----------------
extern "C" void kernel_launch(void* const* d_in, const int* in_sizes, int n_in,
                              void* d_out, int out_size, void* d_ws, size_t ws_size,
                              hipStream_t stream) {
  const int* questions = (const int*)d_in[0];
  const int* responses = (const int*)d_in[1];
  const int* skills    = (const int*)d_in[2];
  const float* q_embed       = (const float*)d_in[4];
  const float* qa_embed      = (const float*)d_in[5];
  const float* q_embed_diff  = (const float*)d_in[6];
  const float* qa_embed_diff = (const float*)d_in[7];
  const float* difficult_param=(const float*)d_in[8];
  const float* ln0_w   = (const float*)d_in[9];
  const float* m_up_w  = (const float*)d_in[10];
  const float* m_up_b  = (const float*)d_in[11];
  const float* m_conv_w= (const float*)d_in[12];
  const float* m_conv_b= (const float*)d_in[13];
  const float* m_q_w   = (const float*)d_in[14];
  const float* m_k_w   = (const float*)d_in[15];
  const float* m_v_w   = (const float*)d_in[16];
  const float* m_ig_w  = (const float*)d_in[17];
  const float* m_ig_b  = (const float*)d_in[18];
  const float* m_fg_w  = (const float*)d_in[19];
  const float* m_fg_b  = (const float*)d_in[20];
  const float* m_outnorm_w=(const float*)d_in[21];
  const float* m_skip  = (const float*)d_in[22];
  const float* m_down_w= (const float*)d_in[23];
  const float* m_down_b= (const float*)d_in[24];
  const float* ln1_w   = (const float*)d_in[25];
  const float* s_conv_w= (const float*)d_in[26];
  const float* s_conv_b= (const float*)d_in[27];
  const float* s_gate_w= (const float*)d_in[28];
  const float* s_rec_w = (const float*)d_in[29];
  const float* s_bias  = (const float*)d_in[30];
  const float* s_gn_w  = (const float*)d_in[31];
  const float* ln2_w   = (const float*)d_in[32];
  const float* ffn_up_w= (const float*)d_in[33];
  const float* ffn_up_b= (const float*)d_in[34];
  const float* ffn_down_w=(const float*)d_in[35];
  const float* ffn_down_b=(const float*)d_in[36];
  const float* postnorm_w=(const float*)d_in[37];
  const float* out_w1  = (const float*)d_in[38];
  const float* out_b1  = (const float*)d_in[39];
  const float* out_w2  = (const float*)d_in[40];
  const float* out_b2  = (const float*)d_in[41];
  const float* out_w3  = (const float*)d_in[42];
  const float* out_b3  = (const float*)d_in[43];

  float* ws = (float*)d_ws;
  const size_t R = (size_t)NP_*256;
  float* x    = ws;
  float* qe   = ws + R;
  float* h    = ws + 2*R;
  float* t256 = ws + 3*R;
  float* A    = ws + 4*R;        // NP x 1024 ; also scan-layout wx
  float* Bb   = ws + 8*R;        // NP x 512
  float* Cb   = ws + 10*R;       // NP x 512  (q; later y_out; later b16)
  float* Db   = ws + 12*R;       // NP x 512  (k; later hout16 / ffg16)
  float* Eb   = ws + 14*R;       // NP x 512  (v; later cq16)
  float* pide = ws + 16*R;
  int*   tgt  = (int*)(ws + 16*R + NP_);
  int*   qsh  = (int*)(ws + 16*R + 2*NP_);
  float* igb  = ws + 16*R + 3*NP_;
  float* fgb  = igb + 64*512;
  float* cs1  = fgb + 64*512;
  float* gdec = cs1 + 64*512;
  float* Mrun = gdec + 64*512;
  bf16* wpool = (bf16*)(Mrun + 64*512);
  bf16* m_down_w16  = wpool;
  bf16* ffn_up_w16  = m_down_w16 + 256*512;
  bf16* ffn_down_w16= ffn_up_w16 + 768*256;
  bf16* out_w1_16   = ffn_down_w16 + 256*384;
  bf16* out_w2_16   = out_w1_16 + 512*1024;
  bf16* h16         = out_w2_16 + 256*512;
  bf16* hout16 = (bf16*)Db;
  bf16* ffg16  = (bf16*)Db;
  bf16* cq16   = (bf16*)Eb;
  bf16* b16    = (bf16*)Cb;

  // ---- one-time weight conversions ----
  k_cvt16<<<(256*512+255)/256,256,0,stream>>>(m_down_w,  m_down_w16,  256*512);
  k_cvt16<<<(768*256+255)/256,256,0,stream>>>(ffn_up_w,  ffn_up_w16,  768*256);
  k_cvt16<<<(256*384+255)/256,256,0,stream>>>(ffn_down_w,ffn_down_w16,256*384);
  k_cvt16<<<(512*1024+255)/256,256,0,stream>>>(out_w1,   out_w1_16,   512*1024);
  k_cvt16<<<(256*512+255)/256,256,0,stream>>>(out_w2,    out_w2_16,   256*512);

  // ---- embeddings (+LN0) ----
  k_embed<<<NP_,256,0,stream>>>(questions,responses,skills,q_embed,qa_embed,
      q_embed_diff,qa_embed_diff,difficult_param, ln0_w, x,qe,h, pide,tgt,qsh);
  // ---- block M ----
  k_gemm<<<dim3(1024/64,NP_/64),256,0,stream>>>(h,256, m_up_w, m_up_b, A, 1024,256,0);
  k_conv_silu<<<(NP_*512)/256,256,0,stream>>>(A,1024, m_conv_w,m_conv_b, Bb,512,512);
  k_headwise<<<(NP_*512)/256,256,0,stream>>>(Bb, A,1024, m_q_w,m_k_w,m_v_w, Cb,Db,Eb);
  k_igfg<<<NROW,256,0,stream>>>(Cb,Db,Eb, m_ig_w,m_ig_b,m_fg_w,m_fg_b, igb,fgb);
  k_decay<<<64,256,0,stream>>>(igb,fgb, cs1,gdec,Mrun);
  k_attn<<<dim3((S_+TQ-1)/TQ, B_*NH_),256,0,stream>>>(Cb,Db,Eb, cs1,gdec,Mrun, m_outnorm_w, A);
  k_hout<<<(NP_*512)/256,256,0,stream>>>(A, Bb, m_skip, hout16);
  k_gemm16<<<dim3(256/64,NP_/64),256,0,stream>>>(hout16, m_down_w16, m_down_b, x, x, (bf16*)nullptr, 256,512,0);
  // ---- block S ----
  k_ln<<<NP_,256,0,stream>>>(x, ln1_w, h);
  k_conv_silu<<<(NP_*256)/256,256,0,stream>>>(h,256, s_conv_w,s_conv_b, Bb,256,256);
  k_wx<<<NROW,256,0,stream>>>(h, Bb, s_gate_w, s_bias, A);
  k_scan<<<64,256,0,stream>>>(A, s_rec_w, Cb);
  k_ynadd_ln2<<<NP_,256,0,stream>>>(Cb, s_gn_w, x, ln2_w, h16);
  // ---- FFN ----
  k_gemm16<<<dim3(768/64,NP_/64),256,0,stream>>>(h16, ffn_up_w16, ffn_up_b, (const float*)nullptr, A, (bf16*)nullptr, 768,256,0);
  k_ffmul<<<(NP_*384)/256,256,0,stream>>>(A, ffg16);
  k_gemm16<<<dim3(256/64,NP_/64),256,0,stream>>>(ffg16, ffn_down_w16, ffn_down_b, x, x, (bf16*)nullptr, 256,384,0);
  // ---- output head ----
  k_cq_ln<<<NP_,256,0,stream>>>(x, postnorm_w, qe, pide, tgt, cq16);
  k_gemm16<<<dim3(512/64,NP_/64),256,0,stream>>>(cq16, out_w1_16, out_b1, (const float*)nullptr, (float*)nullptr, b16, 512,1024,1);
  k_gemm16<<<dim3(256/64,NP_/64),256,0,stream>>>(b16, out_w2_16, out_b2, (const float*)nullptr, t256, (bf16*)nullptr, 256,512,1);
  k_final<<<NROW,256,0,stream>>>(t256, out_w3, out_b3, qsh, (float*)d_out);
}

// Round 11
// 1468.218 us; speedup vs baseline: 1.0590x; 1.0017x over previous
//
#include <hip/hip_runtime.h>
#include <hip/hip_bf16.h>

// ---------------- constants ----------------
#define B_    16
#define SL_   512
#define S_    511
#define E_    256
#define NH_   4
#define I_    512
#define DHM_  128
#define DHS_  64
#define F_    384
#define NP_   8192               // padded row count (multiple of 64)
#define NROW  (B_*S_)            // 8176 real rows
#define EPS_  1e-5f

typedef __hip_bfloat16 bf16;
typedef __bf16 bf16x8v __attribute__((ext_vector_type(8)));
typedef float  f32x4v  __attribute__((ext_vector_type(4)));

__device__ __forceinline__ float sig_(float x){ return 1.f/(1.f+__expf(-x)); }
__device__ __forceinline__ float silu_(float x){ return x*sig_(x); }
__device__ __forceinline__ float logsig_(float x){ return fminf(x,0.f) - log1pf(__expf(-fabsf(x))); }
__device__ __forceinline__ float expneg_(float x){ return __expf(fminf(x,0.f)); }
__device__ __forceinline__ float expclamp_(float x){ return __expf(fminf(fmaxf(x,-80.f),80.f)); }
__device__ __forceinline__ float tanh_(float x){ return 1.f - 2.f/(__expf(2.f*x)+1.f); }
__device__ __forceinline__ float rdlane_(float v, int l){
  return __uint_as_float(__builtin_amdgcn_readlane(__float_as_uint(v), (unsigned)l));
}

// ---------------- f32 -> bf16 weight conversion ----------------
__global__ __launch_bounds__(256) void k_cvt16(const float* __restrict__ src, bf16* __restrict__ dst, int n){
  int i=blockIdx.x*256+threadIdx.x;
  if(i<n) dst[i]=__float2bfloat16(src[i]);
}

// ---------------- embedding gather + fused LN0 ----------------
__global__ __launch_bounds__(256) void k_embed(
  const int* __restrict__ questions, const int* __restrict__ responses, const int* __restrict__ skills,
  const float* __restrict__ q_embed, const float* __restrict__ qa_embed,
  const float* __restrict__ q_embed_diff, const float* __restrict__ qa_embed_diff,
  const float* __restrict__ difficult_param, const float* __restrict__ ln0w,
  float* __restrict__ x, float* __restrict__ qe, float* __restrict__ h,
  float* __restrict__ pide, int* __restrict__ tgt, int* __restrict__ qsh)
{
  __shared__ float red[256];
  int r = blockIdx.x; int e = threadIdx.x;
  float xa = 0.f;
  if (r < NROW){
    int b = r / S_, s = r % S_;
    int pid  = questions[b*SL_+s];
    int qd   = skills[b*SL_+s];
    int resp = responses[b*SL_+s];
    int t    = (resp > -1) ? resp : 0;
    float pe = difficult_param[pid];
    float q0 = q_embed[qd*E_+e];
    xa = q0 + qa_embed[t*E_+e] + pe*qa_embed_diff[t*E_+e];
    float qn = q0 + pe*q_embed_diff[qd*E_+e];
    x[(size_t)r*E_+e]=xa; qe[(size_t)r*E_+e]=qn;
    if (e==0){ pide[r]=pe; tgt[r]=t; qsh[r]=skills[b*SL_+s+1]; }
  } else {
    x[(size_t)r*E_+e]=0.f; qe[(size_t)r*E_+e]=0.f;
    if (e==0){ pide[r]=0.f; tgt[r]=-7; qsh[r]=0; }
  }
  red[e]=xa; __syncthreads();
  for(int s2=128;s2>0;s2>>=1){ if(e<s2) red[e]+=red[e+s2]; __syncthreads(); }
  float mu = red[0]*(1.f/E_); __syncthreads();
  float d = xa-mu;
  red[e]=d*d; __syncthreads();
  for(int s2=128;s2>0;s2>>=1){ if(e<s2) red[e]+=red[e+s2]; __syncthreads(); }
  float var = red[0]*(1.f/E_);
  h[(size_t)r*E_+e] = d*rsqrtf(var+EPS_)*ln0w[e];
}

// ---------------- layernorm over E=256 (used for ln1) ----------------
__global__ __launch_bounds__(256) void k_ln(
  const float* __restrict__ in, const float* __restrict__ w, float* __restrict__ out)
{
  __shared__ float red[256];
  int r = blockIdx.x, t = threadIdx.x;
  float v = in[(size_t)r*E_+t];
  red[t]=v; __syncthreads();
  for(int s=128;s>0;s>>=1){ if(t<s) red[t]+=red[t+s]; __syncthreads(); }
  float mu = red[0]*(1.f/E_); __syncthreads();
  float d = v-mu;
  red[t]=d*d; __syncthreads();
  for(int s=128;s>0;s>>=1){ if(t<s) red[t]+=red[t+s]; __syncthreads(); }
  float var = red[0]*(1.f/E_);
  out[(size_t)r*E_+t] = d*rsqrtf(var+EPS_)*w[t];
}

// ---------------- f32 GEMM (kept for m_up only) ----------------
__global__ __launch_bounds__(256) void k_gemm(
  const float* __restrict__ A, int lda,
  const float* __restrict__ Bw, const float* __restrict__ bias,
  float* __restrict__ C, int M, int K, int relu)
{
  __shared__ __align__(16) float As[16][68];
  __shared__ __align__(16) float Bs[16][68];
  int tid = threadIdx.x;
  int row0 = blockIdx.y*64, col0 = blockIdx.x*64;
  int tm=(tid/16)*4, tn=(tid%16)*4;
  int lk=tid%16, lm=tid/16;
  float acc[4][4]={};
  for(int k0=0;k0<K;k0+=16){
    #pragma unroll
    for(int i=0;i<4;i++){
      int m=lm+i*16;
      As[lk][m]=A[(size_t)(row0+m)*lda + k0+lk];
      Bs[lk][m]=Bw[(size_t)(col0+m)*K + k0+lk];
    }
    __syncthreads();
    #pragma unroll
    for(int k=0;k<16;k++){
      float4 a=*(const float4*)&As[k][tm];
      float4 b=*(const float4*)&Bs[k][tn];
      float av[4]={a.x,a.y,a.z,a.w};
      float bv[4]={b.x,b.y,b.z,b.w};
      #pragma unroll
      for(int i=0;i<4;i++)
        #pragma unroll
        for(int j=0;j<4;j++) acc[i][j]+=av[i]*bv[j];
    }
    __syncthreads();
  }
  #pragma unroll
  for(int i=0;i<4;i++){
    #pragma unroll
    for(int j=0;j<4;j++){
      float v=acc[i][j] + (bias? bias[col0+tn+j] : 0.f);
      if(relu) v=fmaxf(v,0.f);
      C[(size_t)(row0+tm+i)*M + col0+tn+j]=v;
    }
  }
}

// ---------------- bf16 MFMA GEMM (+ optional residual) ----------------
__global__ __launch_bounds__(256) void k_gemm16(
  const bf16* __restrict__ A, const bf16* __restrict__ Bw,
  const float* __restrict__ bias, const float* __restrict__ resid,
  float* __restrict__ C, bf16* __restrict__ C16,
  int M, int K, int relu)
{
  int tid=threadIdx.x;
  int wave=tid>>6, lane=tid&63;
  int wr=wave>>1, wc=wave&1;
  int row0=blockIdx.y*64 + wr*32;
  int col0=blockIdx.x*64 + wc*32;
  int lrow = lane&15, lq = lane>>4;
  f32x4v acc[2][2] = {};
  const bf16* Abase = A  + (size_t)(row0+lrow)*K + lq*8;
  const bf16* Bbase = Bw + (size_t)(col0+lrow)*K + lq*8;
  for(int k0=0;k0<K;k0+=32){
    bf16x8v a0 = *(const bf16x8v*)(Abase + k0);
    bf16x8v a1 = *(const bf16x8v*)(Abase + (size_t)16*K + k0);
    bf16x8v b0 = *(const bf16x8v*)(Bbase + k0);
    bf16x8v b1 = *(const bf16x8v*)(Bbase + (size_t)16*K + k0);
    acc[0][0]=__builtin_amdgcn_mfma_f32_16x16x32_bf16(a0,b0,acc[0][0],0,0,0);
    acc[0][1]=__builtin_amdgcn_mfma_f32_16x16x32_bf16(a0,b1,acc[0][1],0,0,0);
    acc[1][0]=__builtin_amdgcn_mfma_f32_16x16x32_bf16(a1,b0,acc[1][0],0,0,0);
    acc[1][1]=__builtin_amdgcn_mfma_f32_16x16x32_bf16(a1,b1,acc[1][1],0,0,0);
  }
  #pragma unroll
  for(int mi=0;mi<2;mi++){
    #pragma unroll
    for(int ni=0;ni<2;ni++){
      #pragma unroll
      for(int r=0;r<4;r++){
        int row=row0+mi*16+lq*4+r;       // C/D: col=lane&15, row=(lane>>4)*4+reg  [m89]
        int col=col0+ni*16+lrow;
        float v=acc[mi][ni][r] + (bias? bias[col]:0.f);
        if(relu) v=fmaxf(v,0.f);
        if(resid) v += resid[(size_t)row*M+col];
        if(C)   C[(size_t)row*M+col]=v;
        if(C16) C16[(size_t)row*M+col]=__float2bfloat16(v);
      }
    }
  }
}

// ---------------- causal depthwise conv K=4 + silu ----------------
__global__ __launch_bounds__(256) void k_conv_silu(
  const float* __restrict__ in, int ild, const float* __restrict__ w, const float* __restrict__ bws,
  float* __restrict__ out, int old_, int C)
{
  int i = blockIdx.x*256 + threadIdx.x;
  int r = i / C, c = i % C;
  if (r >= NP_) return;
  float acc = 0.f;
  if (r < NROW) {
    int b=r/S_, s=r%S_;
    acc = bws[c];
    #pragma unroll
    for(int j=0;j<4;j++){
      int ss=s-3+j;
      if(ss>=0) acc += w[c*4+j] * in[(size_t)(b*S_+ss)*ild + c];
    }
    acc = silu_(acc);
  }
  out[(size_t)r*old_ + c] = acc;
}

// ---------------- headwise 4x4 block projections q,k,v ----------------
__global__ __launch_bounds__(256) void k_headwise(
  const float* __restrict__ xc, const float* __restrict__ xm, int xmld,
  const float* __restrict__ wq, const float* __restrict__ wk, const float* __restrict__ wv,
  float* __restrict__ q, float* __restrict__ k, float* __restrict__ v)
{
  int i=blockIdx.x*256+threadIdx.x;
  int r=i/I_, c=i%I_;
  if(r>=NP_) return;
  size_t oi=(size_t)r*I_+c;
  if(r>=NROW){ q[oi]=0.f; k[oi]=0.f; v[oi]=0.f; return; }
  int n=c>>2, o=c&3;
  const float* xcr = xc + (size_t)r*I_ + n*4;
  const float* xmr = xm + (size_t)r*xmld + n*4;
  float aq=0.f, ak=0.f, av=0.f;
  #pragma unroll
  for(int d=0;d<4;d++){
    float xcv=xcr[d], xmv=xmr[d];
    aq += xcv*wq[(n*4+o)*4+d];
    ak += xcv*wk[(n*4+o)*4+d];
    av += xmv*wv[(n*4+o)*4+d];
  }
  q[oi]=aq; k[oi]=ak; v[oi]=av;
}

// ---------------- ig/fg gates ----------------
__global__ __launch_bounds__(256) void k_igfg(
  const float* __restrict__ q, const float* __restrict__ k, const float* __restrict__ v,
  const float* __restrict__ wig, const float* __restrict__ big,
  const float* __restrict__ wfg, const float* __restrict__ bfg,
  float* __restrict__ igb, float* __restrict__ fgb)
{
  int r=blockIdx.x;
  int wid=threadIdx.x>>6, lane=threadIdx.x&63;
  int b=r/S_, s=r%S_;
  for(int c=wid; c<8; c+=4){
    int h=c>>1; int isfg=c&1;
    const float* w = isfg? wfg : wig;
    float acc=0.f;
    for(int f=lane; f<1536; f+=64){
      float val = (f<512)? q[(size_t)r*512+f]
                : (f<1024)? k[(size_t)r*512+f-512]
                : v[(size_t)r*512+f-1024];
      acc += val*w[h*1536+f];
    }
    for(int m=32;m;m>>=1) acc+=__shfl_xor(acc,m,64);
    if(lane==0){
      if(isfg) fgb[(b*4+h)*512+s]=acc+bfg[h];
      else     igb[(b*4+h)*512+s]=acc+big[h];
    }
  }
}

// ---------------- decay prep (parallel scans): one block per bh ----------------
__global__ __launch_bounds__(256) void k_decay(
  const float* __restrict__ igb, const float* __restrict__ fgb,
  float* __restrict__ cs1, float* __restrict__ g, float* __restrict__ M)
{
  int bh = blockIdx.x; int tid = threadIdx.x;
  __shared__ float buf[512];
  __shared__ float buf2[512];
  for (int s=tid; s<512; s+=256)
    buf[s] = (s<S_) ? logsig_(fgb[bh*512+s]) : 0.f;
  __syncthreads();
  for (int off=1; off<512; off<<=1){
    int s0=tid, s1=tid+256;
    float v0 = buf[s0] + ((s0>=off)? buf[s0-off] : 0.f);
    float v1 = buf[s1] + ((s1>=off)? buf[s1-off] : 0.f);
    __syncthreads();
    buf[s0]=v0; buf[s1]=v1;
    __syncthreads();
  }
  for (int s=tid; s<512; s+=256){
    float c = buf[s];
    if (s<S_){
      cs1[bh*512+s]=c;
      float gv = igb[bh*512+s]-c;
      g[bh*512+s]=gv;
      buf2[s]=gv;
    } else buf2[s] = -3.4e38f;
  }
  __syncthreads();
  for (int off=1; off<512; off<<=1){
    int s0=tid, s1=tid+256;
    float v0 = fmaxf(buf2[s0], (s0>=off)? buf2[s0-off] : -3.4e38f);
    float v1 = fmaxf(buf2[s1], (s1>=off)? buf2[s1-off] : -3.4e38f);
    __syncthreads();
    buf2[s0]=v0; buf2[s1]=v1;
    __syncthreads();
  }
  for (int s=tid; s<S_; s+=256) M[bh*512+s] = buf2[s];
}

// ---------------- tiled attention (unchanged) ----------------
#define TQ 32
#define TS 32
__global__ __launch_bounds__(256) void k_attn(
  const float* __restrict__ q, const float* __restrict__ k, const float* __restrict__ v,
  const float* __restrict__ cs1, const float* __restrict__ g, const float* __restrict__ M,
  const float* __restrict__ onw, float* __restrict__ hflat)
{
  __shared__ __align__(16) float qs[TQ][132];
  __shared__ __align__(16) float ks[TS][132];
  __shared__ __align__(16) float vs[TS][128];
  __shared__ float Sw[TQ][33];
  __shared__ float MtS[TQ], cssS[TQ], lsumS[TQ], gsS[TS];
  int tq = blockIdx.x, bh = blockIdx.y;
  int b = bh>>2, h = bh&3;
  int tid = threadIdx.x;
  int i = tid>>4, j = tid&15;
  int t0 = tq*TQ;
  {
    int row = tid>>3, c4 = (tid&7)*4;
    const float4* src = (const float4*)(q + (size_t)(b*S_ + t0 + row)*512 + h*128);
    float4* dst = (float4*)&qs[row][0];
    #pragma unroll
    for(int c=0;c<4;c++) dst[c4+c] = src[c4+c];
  }
  if (tid < TQ){
    int t = t0 + tid; int tc = (t<S_)? t : (S_-1);
    MtS[tid]  = M[bh*512 + tc];
    cssS[tid] = cs1[bh*512 + tc];
    lsumS[tid]= 0.f;
  }
  float o[2][8] = {};
  int t1 = min(t0+TQ, S_);
  int nst = (t1 + TS - 1)/TS;
  const float sc = 0.08838834764831843f;
  for (int st=0; st<nst; ++st){
    int s0 = st*TS;
    __syncthreads();
    {
      int row = tid>>3, c4 = (tid&7)*4;
      const float4* srck = (const float4*)(k + (size_t)(b*S_ + s0 + row)*512 + h*128);
      const float4* srcv = (const float4*)(v + (size_t)(b*S_ + s0 + row)*512 + h*128);
      float4* dk = (float4*)&ks[row][0];
      float4* dv = (float4*)&vs[row][0];
      #pragma unroll
      for(int c=0;c<4;c++){ dk[c4+c]=srck[c4+c]; dv[c4+c]=srcv[c4+c]; }
      if (tid < TS) gsS[tid] = g[bh*512 + s0 + tid];
    }
    __syncthreads();
    float a00=0,a01=0,a10=0,a11=0;
    {
      const float4* q0 = (const float4*)&qs[i*2][0];
      const float4* q1 = (const float4*)&qs[i*2+1][0];
      const float4* k0 = (const float4*)&ks[j][0];
      const float4* k1 = (const float4*)&ks[j+16][0];
      #pragma unroll
      for(int d4=0; d4<32; ++d4){
        float4 qa=q0[d4], qb=q1[d4], ka=k0[d4], kb=k1[d4];
        a00 += qa.x*ka.x+qa.y*ka.y+qa.z*ka.z+qa.w*ka.w;
        a01 += qa.x*kb.x+qa.y*kb.y+qa.z*kb.z+qa.w*kb.w;
        a10 += qb.x*ka.x+qb.y*ka.y+qb.z*ka.z+qb.w*ka.w;
        a11 += qb.x*kb.x+qb.y*kb.y+qb.z*kb.z+qb.w*kb.w;
      }
    }
    int tA = t0 + i*2, tB = tA+1;
    int sA = s0 + j,   sB = sA + 16;
    float gA = gsS[j], gB = gsS[j+16];
    float mA = MtS[i*2], mB = MtS[i*2+1];
    float w00 = (sA<=tA)? a00*sc*expneg_(gA-mA) : 0.f;
    float w01 = (sB<=tA)? a01*sc*expneg_(gB-mA) : 0.f;
    float w10 = (sA<=tB)? a10*sc*expneg_(gA-mB) : 0.f;
    float w11 = (sB<=tB)? a11*sc*expneg_(gB-mB) : 0.f;
    float r0 = w00+w01, r1 = w10+w11;
    #pragma unroll
    for(int msk=1; msk<16; msk<<=1){ r0 += __shfl_xor(r0,msk,16); r1 += __shfl_xor(r1,msk,16); }
    if (j==0){ lsumS[i*2] += r0; lsumS[i*2+1] += r1; }
    Sw[i*2][j]     = w00; Sw[i*2][j+16]   = w01;
    Sw[i*2+1][j]   = w10; Sw[i*2+1][j+16] = w11;
    __syncthreads();
    #pragma unroll 8
    for(int s=0;s<TS;s++){
      float w0 = Sw[i*2][s], w1 = Sw[i*2+1][s];
      float4 v0 = *(const float4*)&vs[s][j*4];
      float4 v1 = *(const float4*)&vs[s][64+j*4];
      o[0][0]+=w0*v0.x; o[0][1]+=w0*v0.y; o[0][2]+=w0*v0.z; o[0][3]+=w0*v0.w;
      o[0][4]+=w0*v1.x; o[0][5]+=w0*v1.y; o[0][6]+=w0*v1.z; o[0][7]+=w0*v1.w;
      o[1][0]+=w1*v0.x; o[1][1]+=w1*v0.y; o[1][2]+=w1*v0.z; o[1][3]+=w1*v0.w;
      o[1][4]+=w1*v1.x; o[1][5]+=w1*v1.y; o[1][6]+=w1*v1.z; o[1][7]+=w1*v1.w;
    }
  }
  __syncthreads();
  #pragma unroll
  for(int r=0;r<2;r++){
    int tl = i*2+r;
    int t = t0 + tl;
    float maxD = cssS[tl] + MtS[tl];
    float norm = fmaxf(fabsf(lsumS[tl]), expclamp_(-maxD));
    float scale = 1.f/(norm+1e-6f);
    float sum=0.f;
    #pragma unroll
    for(int d=0;d<8;d++){ o[r][d]*=scale; sum+=o[r][d]; }
    #pragma unroll
    for(int msk=1; msk<16; msk<<=1) sum += __shfl_xor(sum,msk,16);
    float mu = sum*(1.f/128.f);
    float var=0.f;
    #pragma unroll
    for(int d=0;d<8;d++){ float dd=o[r][d]-mu; var+=dd*dd; }
    #pragma unroll
    for(int msk=1; msk<16; msk<<=1) var += __shfl_xor(var,msk,16);
    float rs = rsqrtf(var*(1.f/128.f)+EPS_);
    if (t < S_){
      float* dst = hflat + (size_t)(b*S_+t)*1024 + h*128;
      #pragma unroll
      for(int c=0;c<4;c++) dst[j*4+c]    = (o[r][c]  -mu)*rs*onw[h*128+j*4+c];
      #pragma unroll
      for(int c=0;c<4;c++) dst[64+j*4+c] = (o[r][4+c]-mu)*rs*onw[h*128+64+j*4+c];
    }
  }
}

// ---------------- hout = (hflat + skip*xc) * silu(z) -> bf16 ----------------
__global__ __launch_bounds__(256) void k_hout(
  const float* __restrict__ A, const float* __restrict__ xc, const float* __restrict__ skip,
  bf16* __restrict__ out16)
{
  int i=blockIdx.x*256+threadIdx.x;
  int r=i/512, c=i%512;
  float hf=A[(size_t)r*1024+c];
  float z =A[(size_t)r*1024+512+c];
  out16[(size_t)r*512+c] = __float2bfloat16((hf + skip[c]*xc[(size_t)r*512+c]) * silu_(z));
}

// ---------------- wx = gate pre-activations, scan layout [bn][s][g*64+e] ----------------
__global__ __launch_bounds__(256) void k_wx(
  const float* __restrict__ h, const float* __restrict__ hc,
  const float* __restrict__ gw, const float* __restrict__ gb,
  float* __restrict__ wx)
{
  __shared__ float hs[256], hcs[256];
  int r=blockIdx.x; int t=threadIdx.x;
  hs[t]=h[(size_t)r*256+t]; hcs[t]=hc[(size_t)r*256+t];
  __syncthreads();
  int b=r/S_, s=r%S_;
  int n=t>>6, e=t&63;
  #pragma unroll
  for(int gg=0; gg<4; gg++){
    const float* src = (gg<2? hcs: hs) + n*64;
    const float* wp = gw + (size_t)(((gg*4+n)*64+e))*64;
    float acc=gb[(gg*4+n)*64+e];
    #pragma unroll 8
    for(int d=0;d<64;d++) acc+=src[d]*wp[d];
    wx[((size_t)(b*4+n)*512 + s)*256 + gg*64 + e]=acc;
  }
}

// ---------------- sLSTM scan: readlane matvec + chunked LDS y-buffer ----------------
// Per-step barrier drains only LDS ops; global y_out stores + wx prefetch loads are
// drained once per 32-step flush (amortized).
#define YCH 32
__global__ __launch_bounds__(256,1) void k_scan(
  const float* __restrict__ wx, const float* __restrict__ rw, float* __restrict__ y_out)
{
  int bn = blockIdx.x; int b = bn>>2, n = bn&3;
  int tid = threadIdx.x; int g = tid>>6, e = tid&63;
  float W[64];
  #pragma unroll
  for(int d=0;d<64;d++) W[d]=rw[(size_t)(((g*4+n)*64+d))*64 + e];
  __shared__ float rawS[2][256];
  __shared__ __align__(16) float wxS[2][YCH*256];
  __shared__ float ybuf[YCH*64];
  const float* wxBase = wx + (size_t)bn*512*256;
  { // stage chunk 0
    const float4* src=(const float4*)wxBase;
    float4* dst=(float4*)&wxS[0][0];
    #pragma unroll
    for(int j=0;j<8;j++) dst[j*256+tid]=src[j*256+tid];
  }
  float c=0.f, nn=0.f, m=0.f, yreg=0.f;
  __syncthreads();
  for (int s=0; s<S_; ++s){
    int sl = s & (YCH-1);
    int p  = s & 1;
    float wxv = wxS[(s>>5)&1][sl*256 + tid];
    float a0=0.f,a1=0.f,a2=0.f,a3=0.f;
    #pragma unroll
    for(int d=0; d<64; d+=4){
      a0 += rdlane_(yreg,d  )*W[d  ];
      a1 += rdlane_(yreg,d+1)*W[d+1];
      a2 += rdlane_(yreg,d+2)*W[d+2];
      a3 += rdlane_(yreg,d+3)*W[d+3];
    }
    rawS[p][tid] = wxv + ((a0+a1)+(a2+a3));
    __syncthreads();
    float iraw=rawS[p][e], fraw=rawS[p][64+e], zraw=rawS[p][128+e], oraw=rawS[p][192+e];
    float lfm = m + logsig_(fraw);
    float mnew = fmaxf(iraw, lfm);
    float ig = expneg_(iraw-mnew), fg=expneg_(lfm-mnew);
    c  = fg*c  + ig*tanh_(zraw);
    nn = fmaxf(fg*nn + ig, 1e-30f);
    float y = sig_(oraw) * c / nn;
    m = mnew;
    yreg = y;
    if (g==0) ybuf[sl*64+e] = y;
    if (sl==YCH-1 || s==S_-1){
      __syncthreads();                    // make wave-0's ybuf writes visible
      int s0 = s-sl;
      int cnt = (sl+1)*64;
      for(int idx=tid; idx<cnt; idx+=256){
        int ss=s0+(idx>>6), ee=idx&63;
        y_out[((size_t)b*S_+ss)*256 + n*64 + ee] = ybuf[idx];
      }
      int nch=(s>>5)+1;
      if (nch<16){
        const float4* src=(const float4*)(wxBase+(size_t)nch*YCH*256);
        float4* dst=(float4*)&wxS[nch&1][0];
        #pragma unroll
        for(int j=0;j<8;j++) dst[j*256+tid]=src[j*256+tid];
      }
      __syncthreads();                    // WAR-protect ybuf + publish next wx chunk
    }
  }
}

// ---------------- yn-add + fused LN2 -> bf16 ----------------
__global__ __launch_bounds__(256) void k_ynadd_ln2(
  const float* __restrict__ y, const float* __restrict__ gn,
  float* __restrict__ x, const float* __restrict__ ln2w, bf16* __restrict__ h16)
{
  __shared__ float red[256];
  int r=blockIdx.x, t=threadIdx.x;
  float xv = x[(size_t)r*256+t];
  if (r < NROW){
    float v=y[(size_t)r*256+t];
    float s=v;
    for(int m=32;m;m>>=1) s+=__shfl_xor(s,m,64);
    float mu=s*(1.f/64.f);
    float d=v-mu;
    float q=d*d;
    for(int m=32;m;m>>=1) q+=__shfl_xor(q,m,64);
    float var=q*(1.f/64.f);
    xv += d*rsqrtf(var+EPS_)*gn[t];
    x[(size_t)r*256+t]=xv;
  }
  red[t]=xv; __syncthreads();
  for(int s=128;s>0;s>>=1){ if(t<s) red[t]+=red[t+s]; __syncthreads(); }
  float mu2=red[0]*(1.f/E_); __syncthreads();
  float dd=xv-mu2;
  red[t]=dd*dd; __syncthreads();
  for(int s=128;s>0;s>>=1){ if(t<s) red[t]+=red[t+s]; __syncthreads(); }
  float var2=red[0]*(1.f/E_);
  h16[(size_t)r*256+t]=__float2bfloat16(dd*rsqrtf(var2+EPS_)*ln2w[t]);
}

// ---------------- ffn gate: relu(gate)*upf -> bf16 ----------------
__global__ __launch_bounds__(256) void k_ffmul(const float* __restrict__ ffu, bf16* __restrict__ out)
{
  int i=blockIdx.x*256+threadIdx.x;
  int r=i/384, j=i%384;
  out[(size_t)r*384+j] = __float2bfloat16(fmaxf(ffu[(size_t)r*768+j],0.f)*ffu[(size_t)r*768+384+j]);
}

// ---------------- fused postnorm-LN + cq build -> bf16 ----------------
__global__ __launch_bounds__(256) void k_cq_ln(
  const float* __restrict__ x, const float* __restrict__ pw,
  const float* __restrict__ qe, const float* __restrict__ pide, const int* __restrict__ tgt,
  bf16* __restrict__ cq)
{
  __shared__ float red[256];
  int r=blockIdx.x, t=threadIdx.x;
  float v = x[(size_t)r*256+t];
  red[t]=v; __syncthreads();
  for(int s=128;s>0;s>>=1){ if(t<s) red[t]+=red[t+s]; __syncthreads(); }
  float mu=red[0]*(1.f/E_); __syncthreads();
  float d=v-mu;
  red[t]=d*d; __syncthreads();
  for(int s=128;s>0;s>>=1){ if(t<s) red[t]+=red[t+s]; __syncthreads(); }
  float var=red[0]*(1.f/E_);
  float dv = d*rsqrtf(var+EPS_)*pw[t];
  float pe=pide[r]; int tg=tgt[r];
  size_t base=(size_t)r*1024;
  cq[base+t]=__float2bfloat16(dv-pe);
  cq[base+256+t]=__float2bfloat16(qe[(size_t)r*256+t]);
  cq[base+512+t]=__float2bfloat16((tg==1)? dv:0.f);
  cq[base+768+t]=__float2bfloat16((tg==0)? dv:0.f);
}

// ---------------- final: selected logit + sigmoid ----------------
__global__ __launch_bounds__(256) void k_final(
  const float* __restrict__ o2, const float* __restrict__ w3, const float* __restrict__ b3,
  const int* __restrict__ qsh, float* __restrict__ out)
{
  __shared__ float red[256];
  int r=blockIdx.x, t=threadIdx.x;
  int qi=qsh[r];
  float p=o2[(size_t)r*256+t]*w3[(size_t)qi*256+t];
  red[t]=p; __syncthreads();
  for(int s=128;s>0;s>>=1){ if(t<s) red[t]+=red[t+s]; __syncthreads(); }
  if(t==0) out[r]=sig_(red[0]+b3[qi]);
}

// ---------------- launch ----------------
extern "C" void kernel_launch(void* const* d_in, const int* in_sizes, int n_in,
                              void* d_out, int out_size, void* d_ws, size_t ws_size,
                              hipStream_t stream) {
  const int* questions = (const int*)d_in[0];
  const int* responses = (const int*)d_in[1];
  const int* skills    = (const int*)d_in[2];
  const float* q_embed       = (const float*)d_in[4];
  const float* qa_embed      = (const float*)d_in[5];
  const float* q_embed_diff  = (const float*)d_in[6];
  const float* qa_embed_diff = (const float*)d_in[7];
  const float* difficult_param=(const float*)d_in[8];
  const float* ln0_w   = (const float*)d_in[9];
  const float* m_up_w  = (const float*)d_in[10];
  const float* m_up_b  = (const float*)d_in[11];
  const float* m_conv_w= (const float*)d_in[12];
  const float* m_conv_b= (const float*)d_in[13];
  const float* m_q_w   = (const float*)d_in[14];
  const float* m_k_w   = (const float*)d_in[15];
  const float* m_v_w   = (const float*)d_in[16];
  const float* m_ig_w  = (const float*)d_in[17];
  const float* m_ig_b  = (const float*)d_in[18];
  const float* m_fg_w  = (const float*)d_in[19];
  const float* m_fg_b  = (const float*)d_in[20];
  const float* m_outnorm_w=(const float*)d_in[21];
  const float* m_skip  = (const float*)d_in[22];
  const float* m_down_w= (const float*)d_in[23];
  const float* m_down_b= (const float*)d_in[24];
  const float* ln1_w   = (const float*)d_in[25];
  const float* s_conv_w= (const float*)d_in[26];
  const float* s_conv_b= (const float*)d_in[27];
  const float* s_gate_w= (const float*)d_in[28];
  const float* s_rec_w = (const float*)d_in[29];
  const float* s_bias  = (const float*)d_in[30];
  const float* s_gn_w  = (const float*)d_in[31];
  const float* ln2_w   = (const float*)d_in[32];
  const float* ffn_up_w= (const float*)d_in[33];
  const float* ffn_up_b= (const float*)d_in[34];
  const float* ffn_down_w=(const float*)d_in[35];
  const float* ffn_down_b=(const float*)d_in[36];
  const float* postnorm_w=(const float*)d_in[37];
  const float* out_w1  = (const float*)d_in[38];
  const float* out_b1  = (const float*)d_in[39];
  const float* out_w2  = (const float*)d_in[40];
  const float* out_b2  = (const float*)d_in[41];
  const float* out_w3  = (const float*)d_in[42];
  const float* out_b3  = (const float*)d_in[43];

  float* ws = (float*)d_ws;
  const size_t R = (size_t)NP_*256;
  float* x    = ws;
  float* qe   = ws + R;
  float* h    = ws + 2*R;
  float* t256 = ws + 3*R;
  float* A    = ws + 4*R;        // NP x 1024 ; also scan-layout wx
  float* Bb   = ws + 8*R;        // NP x 512
  float* Cb   = ws + 10*R;       // NP x 512  (q; later y_out; later b16)
  float* Db   = ws + 12*R;       // NP x 512  (k; later hout16 / ffg16)
  float* Eb   = ws + 14*R;       // NP x 512  (v; later cq16)
  float* pide = ws + 16*R;
  int*   tgt  = (int*)(ws + 16*R + NP_);
  int*   qsh  = (int*)(ws + 16*R + 2*NP_);
  float* igb  = ws + 16*R + 3*NP_;
  float* fgb  = igb + 64*512;
  float* cs1  = fgb + 64*512;
  float* gdec = cs1 + 64*512;
  float* Mrun = gdec + 64*512;
  bf16* wpool = (bf16*)(Mrun + 64*512);
  bf16* m_down_w16  = wpool;
  bf16* ffn_up_w16  = m_down_w16 + 256*512;
  bf16* ffn_down_w16= ffn_up_w16 + 768*256;
  bf16* out_w1_16   = ffn_down_w16 + 256*384;
  bf16* out_w2_16   = out_w1_16 + 512*1024;
  bf16* h16         = out_w2_16 + 256*512;
  bf16* hout16 = (bf16*)Db;
  bf16* ffg16  = (bf16*)Db;
  bf16* cq16   = (bf16*)Eb;
  bf16* b16    = (bf16*)Cb;

  // ---- one-time weight conversions ----
  k_cvt16<<<(256*512+255)/256,256,0,stream>>>(m_down_w,  m_down_w16,  256*512);
  k_cvt16<<<(768*256+255)/256,256,0,stream>>>(ffn_up_w,  ffn_up_w16,  768*256);
  k_cvt16<<<(256*384+255)/256,256,0,stream>>>(ffn_down_w,ffn_down_w16,256*384);
  k_cvt16<<<(512*1024+255)/256,256,0,stream>>>(out_w1,   out_w1_16,   512*1024);
  k_cvt16<<<(256*512+255)/256,256,0,stream>>>(out_w2,    out_w2_16,   256*512);

  // ---- embeddings (+LN0) ----
  k_embed<<<NP_,256,0,stream>>>(questions,responses,skills,q_embed,qa_embed,
      q_embed_diff,qa_embed_diff,difficult_param, ln0_w, x,qe,h, pide,tgt,qsh);
  // ---- block M ----
  k_gemm<<<dim3(1024/64,NP_/64),256,0,stream>>>(h,256, m_up_w, m_up_b, A, 1024,256,0);
  k_conv_silu<<<(NP_*512)/256,256,0,stream>>>(A,1024, m_conv_w,m_conv_b, Bb,512,512);
  k_headwise<<<(NP_*512)/256,256,0,stream>>>(Bb, A,1024, m_q_w,m_k_w,m_v_w, Cb,Db,Eb);
  k_igfg<<<NROW,256,0,stream>>>(Cb,Db,Eb, m_ig_w,m_ig_b,m_fg_w,m_fg_b, igb,fgb);
  k_decay<<<64,256,0,stream>>>(igb,fgb, cs1,gdec,Mrun);
  k_attn<<<dim3((S_+TQ-1)/TQ, B_*NH_),256,0,stream>>>(Cb,Db,Eb, cs1,gdec,Mrun, m_outnorm_w, A);
  k_hout<<<(NP_*512)/256,256,0,stream>>>(A, Bb, m_skip, hout16);
  k_gemm16<<<dim3(256/64,NP_/64),256,0,stream>>>(hout16, m_down_w16, m_down_b, x, x, (bf16*)nullptr, 256,512,0);
  // ---- block S ----
  k_ln<<<NP_,256,0,stream>>>(x, ln1_w, h);
  k_conv_silu<<<(NP_*256)/256,256,0,stream>>>(h,256, s_conv_w,s_conv_b, Bb,256,256);
  k_wx<<<NROW,256,0,stream>>>(h, Bb, s_gate_w, s_bias, A);
  k_scan<<<64,256,0,stream>>>(A, s_rec_w, Cb);
  k_ynadd_ln2<<<NP_,256,0,stream>>>(Cb, s_gn_w, x, ln2_w, h16);
  // ---- FFN ----
  k_gemm16<<<dim3(768/64,NP_/64),256,0,stream>>>(h16, ffn_up_w16, ffn_up_b, (const float*)nullptr, A, (bf16*)nullptr, 768,256,0);
  k_ffmul<<<(NP_*384)/256,256,0,stream>>>(A, ffg16);
  k_gemm16<<<dim3(256/64,NP_/64),256,0,stream>>>(ffg16, ffn_down_w16, ffn_down_b, x, x, (bf16*)nullptr, 256,384,0);
  // ---- output head ----
  k_cq_ln<<<NP_,256,0,stream>>>(x, postnorm_w, qe, pide, tgt, cq16);
  k_gemm16<<<dim3(512/64,NP_/64),256,0,stream>>>(cq16, out_w1_16, out_b1, (const float*)nullptr, (float*)nullptr, b16, 512,1024,1);
  k_gemm16<<<dim3(256/64,NP_/64),256,0,stream>>>(b16, out_w2_16, out_b2, (const float*)nullptr, t256, (bf16*)nullptr, 256,512,1);
  k_final<<<NROW,256,0,stream>>>(t256, out_w3, out_b3, qsh, (float*)d_out);
}

// Round 12
// 1365.101 us; speedup vs baseline: 1.1390x; 1.0755x over previous
//
#include <hip/hip_runtime.h>
#include <hip/hip_bf16.h>

// ---------------- constants ----------------
#define B_    16
#define SL_   512
#define S_    511
#define E_    256
#define NH_   4
#define I_    512
#define DHM_  128
#define DHS_  64
#define F_    384
#define NP_   8192               // padded row count (multiple of 64)
#define NROW  (B_*S_)            // 8176 real rows
#define EPS_  1e-5f

typedef __hip_bfloat16 bf16;
typedef __bf16 bf16x8v __attribute__((ext_vector_type(8)));
typedef float  f32x4v  __attribute__((ext_vector_type(4)));

__device__ __forceinline__ float rcp_(float x){ return __builtin_amdgcn_rcpf(x); }
__device__ __forceinline__ float sig_(float x){ return rcp_(1.f+__expf(-x)); }
__device__ __forceinline__ float silu_(float x){ return x*sig_(x); }
__device__ __forceinline__ float logsig_(float x){ return fminf(x,0.f) - __logf(1.f + __expf(-fabsf(x))); }
__device__ __forceinline__ float expneg_(float x){ return __expf(fminf(x,0.f)); }
__device__ __forceinline__ float expclamp_(float x){ return __expf(fminf(fmaxf(x,-80.f),80.f)); }
__device__ __forceinline__ float tanh_(float x){ return 1.f - 2.f*rcp_(__expf(2.f*x)+1.f); }
__device__ __forceinline__ float rdlane_(float v, int l){
  return __uint_as_float(__builtin_amdgcn_readlane(__float_as_uint(v), (unsigned)l));
}

// ---------------- f32 -> bf16 weight conversion ----------------
__global__ __launch_bounds__(256) void k_cvt16(const float* __restrict__ src, bf16* __restrict__ dst, int n){
  int i=blockIdx.x*256+threadIdx.x;
  if(i<n) dst[i]=__float2bfloat16(src[i]);
}
// ---------------- f32 -> split bf16 (hi+lo) conversion ----------------
__global__ __launch_bounds__(256) void k_cvtsplit(const float* __restrict__ src,
  bf16* __restrict__ hi, bf16* __restrict__ lo, int n){
  int i=blockIdx.x*256+threadIdx.x;
  if(i<n){
    float v=src[i];
    bf16 h=__float2bfloat16(v);
    hi[i]=h;
    lo[i]=__float2bfloat16(v-__bfloat162float(h));
  }
}

// ---------------- embedding gather + fused LN0 -> split bf16 ----------------
__global__ __launch_bounds__(256) void k_embed(
  const int* __restrict__ questions, const int* __restrict__ responses, const int* __restrict__ skills,
  const float* __restrict__ q_embed, const float* __restrict__ qa_embed,
  const float* __restrict__ q_embed_diff, const float* __restrict__ qa_embed_diff,
  const float* __restrict__ difficult_param, const float* __restrict__ ln0w,
  float* __restrict__ x, float* __restrict__ qe,
  bf16* __restrict__ h_hi, bf16* __restrict__ h_lo,
  float* __restrict__ pide, int* __restrict__ tgt, int* __restrict__ qsh)
{
  __shared__ float red[256];
  int r = blockIdx.x; int e = threadIdx.x;
  float xa = 0.f;
  if (r < NROW){
    int b = r / S_, s = r % S_;
    int pid  = questions[b*SL_+s];
    int qd   = skills[b*SL_+s];
    int resp = responses[b*SL_+s];
    int t    = (resp > -1) ? resp : 0;
    float pe = difficult_param[pid];
    float q0 = q_embed[qd*E_+e];
    xa = q0 + qa_embed[t*E_+e] + pe*qa_embed_diff[t*E_+e];
    float qn = q0 + pe*q_embed_diff[qd*E_+e];
    x[(size_t)r*E_+e]=xa; qe[(size_t)r*E_+e]=qn;
    if (e==0){ pide[r]=pe; tgt[r]=t; qsh[r]=skills[b*SL_+s+1]; }
  } else {
    x[(size_t)r*E_+e]=0.f; qe[(size_t)r*E_+e]=0.f;
    if (e==0){ pide[r]=0.f; tgt[r]=-7; qsh[r]=0; }
  }
  red[e]=xa; __syncthreads();
  for(int s2=128;s2>0;s2>>=1){ if(e<s2) red[e]+=red[e+s2]; __syncthreads(); }
  float mu = red[0]*(1.f/E_); __syncthreads();
  float d = xa-mu;
  red[e]=d*d; __syncthreads();
  for(int s2=128;s2>0;s2>>=1){ if(e<s2) red[e]+=red[e+s2]; __syncthreads(); }
  float var = red[0]*(1.f/E_);
  float o = d*rsqrtf(var+EPS_)*ln0w[e];
  bf16 hv = __float2bfloat16(o);
  h_hi[(size_t)r*E_+e] = hv;
  h_lo[(size_t)r*E_+e] = __float2bfloat16(o-__bfloat162float(hv));
}

// ---------------- layernorm over E=256 (used for ln1) ----------------
__global__ __launch_bounds__(256) void k_ln(
  const float* __restrict__ in, const float* __restrict__ w, float* __restrict__ out)
{
  __shared__ float red[256];
  int r = blockIdx.x, t = threadIdx.x;
  float v = in[(size_t)r*E_+t];
  red[t]=v; __syncthreads();
  for(int s=128;s>0;s>>=1){ if(t<s) red[t]+=red[t+s]; __syncthreads(); }
  float mu = red[0]*(1.f/E_); __syncthreads();
  float d = v-mu;
  red[t]=d*d; __syncthreads();
  for(int s=128;s>0;s>>=1){ if(t<s) red[t]+=red[t+s]; __syncthreads(); }
  float var = red[0]*(1.f/E_);
  out[(size_t)r*E_+t] = d*rsqrtf(var+EPS_)*w[t];
}

// ---------------- split-bf16 MFMA GEMM: C = (Ah+Al)(Bh+Bl)^T + bias (drop lo*lo) ----------------
__global__ __launch_bounds__(256) void k_gemm16s(
  const bf16* __restrict__ Ah, const bf16* __restrict__ Al,
  const bf16* __restrict__ Bh, const bf16* __restrict__ Bl,
  const float* __restrict__ bias, float* __restrict__ C, int M, int K)
{
  int tid=threadIdx.x;
  int wave=tid>>6, lane=tid&63;
  int wr=wave>>1, wc=wave&1;
  int row0=blockIdx.y*64 + wr*32;
  int col0=blockIdx.x*64 + wc*32;
  int lrow = lane&15, lq = lane>>4;
  f32x4v acc[2][2] = {};
  size_t aoff = (size_t)(row0+lrow)*K + lq*8;
  size_t boff = (size_t)(col0+lrow)*K + lq*8;
  for(int k0=0;k0<K;k0+=32){
    bf16x8v ah0=*(const bf16x8v*)(Ah+aoff+k0), ah1=*(const bf16x8v*)(Ah+aoff+(size_t)16*K+k0);
    bf16x8v al0=*(const bf16x8v*)(Al+aoff+k0), al1=*(const bf16x8v*)(Al+aoff+(size_t)16*K+k0);
    bf16x8v bh0=*(const bf16x8v*)(Bh+boff+k0), bh1=*(const bf16x8v*)(Bh+boff+(size_t)16*K+k0);
    bf16x8v bl0=*(const bf16x8v*)(Bl+boff+k0), bl1=*(const bf16x8v*)(Bl+boff+(size_t)16*K+k0);
    acc[0][0]=__builtin_amdgcn_mfma_f32_16x16x32_bf16(ah0,bh0,acc[0][0],0,0,0);
    acc[0][1]=__builtin_amdgcn_mfma_f32_16x16x32_bf16(ah0,bh1,acc[0][1],0,0,0);
    acc[1][0]=__builtin_amdgcn_mfma_f32_16x16x32_bf16(ah1,bh0,acc[1][0],0,0,0);
    acc[1][1]=__builtin_amdgcn_mfma_f32_16x16x32_bf16(ah1,bh1,acc[1][1],0,0,0);
    acc[0][0]=__builtin_amdgcn_mfma_f32_16x16x32_bf16(ah0,bl0,acc[0][0],0,0,0);
    acc[0][1]=__builtin_amdgcn_mfma_f32_16x16x32_bf16(ah0,bl1,acc[0][1],0,0,0);
    acc[1][0]=__builtin_amdgcn_mfma_f32_16x16x32_bf16(ah1,bl0,acc[1][0],0,0,0);
    acc[1][1]=__builtin_amdgcn_mfma_f32_16x16x32_bf16(ah1,bl1,acc[1][1],0,0,0);
    acc[0][0]=__builtin_amdgcn_mfma_f32_16x16x32_bf16(al0,bh0,acc[0][0],0,0,0);
    acc[0][1]=__builtin_amdgcn_mfma_f32_16x16x32_bf16(al0,bh1,acc[0][1],0,0,0);
    acc[1][0]=__builtin_amdgcn_mfma_f32_16x16x32_bf16(al1,bh0,acc[1][0],0,0,0);
    acc[1][1]=__builtin_amdgcn_mfma_f32_16x16x32_bf16(al1,bh1,acc[1][1],0,0,0);
  }
  #pragma unroll
  for(int mi=0;mi<2;mi++){
    #pragma unroll
    for(int ni=0;ni<2;ni++){
      #pragma unroll
      for(int r=0;r<4;r++){
        int row=row0+mi*16+lq*4+r;
        int col=col0+ni*16+lrow;
        C[(size_t)row*M+col]=acc[mi][ni][r] + bias[col];
      }
    }
  }
}

// ---------------- bf16 MFMA GEMM (+ optional residual) ----------------
__global__ __launch_bounds__(256) void k_gemm16(
  const bf16* __restrict__ A, const bf16* __restrict__ Bw,
  const float* __restrict__ bias, const float* __restrict__ resid,
  float* __restrict__ C, bf16* __restrict__ C16,
  int M, int K, int relu)
{
  int tid=threadIdx.x;
  int wave=tid>>6, lane=tid&63;
  int wr=wave>>1, wc=wave&1;
  int row0=blockIdx.y*64 + wr*32;
  int col0=blockIdx.x*64 + wc*32;
  int lrow = lane&15, lq = lane>>4;
  f32x4v acc[2][2] = {};
  const bf16* Abase = A  + (size_t)(row0+lrow)*K + lq*8;
  const bf16* Bbase = Bw + (size_t)(col0+lrow)*K + lq*8;
  for(int k0=0;k0<K;k0+=32){
    bf16x8v a0 = *(const bf16x8v*)(Abase + k0);
    bf16x8v a1 = *(const bf16x8v*)(Abase + (size_t)16*K + k0);
    bf16x8v b0 = *(const bf16x8v*)(Bbase + k0);
    bf16x8v b1 = *(const bf16x8v*)(Bbase + (size_t)16*K + k0);
    acc[0][0]=__builtin_amdgcn_mfma_f32_16x16x32_bf16(a0,b0,acc[0][0],0,0,0);
    acc[0][1]=__builtin_amdgcn_mfma_f32_16x16x32_bf16(a0,b1,acc[0][1],0,0,0);
    acc[1][0]=__builtin_amdgcn_mfma_f32_16x16x32_bf16(a1,b0,acc[1][0],0,0,0);
    acc[1][1]=__builtin_amdgcn_mfma_f32_16x16x32_bf16(a1,b1,acc[1][1],0,0,0);
  }
  #pragma unroll
  for(int mi=0;mi<2;mi++){
    #pragma unroll
    for(int ni=0;ni<2;ni++){
      #pragma unroll
      for(int r=0;r<4;r++){
        int row=row0+mi*16+lq*4+r;       // C/D: col=lane&15, row=(lane>>4)*4+reg  [m89]
        int col=col0+ni*16+lrow;
        float v=acc[mi][ni][r] + (bias? bias[col]:0.f);
        if(relu) v=fmaxf(v,0.f);
        if(resid) v += resid[(size_t)row*M+col];
        if(C)   C[(size_t)row*M+col]=v;
        if(C16) C16[(size_t)row*M+col]=__float2bfloat16(v);
      }
    }
  }
}

// ---------------- causal depthwise conv K=4 + silu ----------------
__global__ __launch_bounds__(256) void k_conv_silu(
  const float* __restrict__ in, int ild, const float* __restrict__ w, const float* __restrict__ bws,
  float* __restrict__ out, int old_, int C)
{
  int i = blockIdx.x*256 + threadIdx.x;
  int r = i / C, c = i % C;
  if (r >= NP_) return;
  float acc = 0.f;
  if (r < NROW) {
    int b=r/S_, s=r%S_;
    acc = bws[c];
    #pragma unroll
    for(int j=0;j<4;j++){
      int ss=s-3+j;
      if(ss>=0) acc += w[c*4+j] * in[(size_t)(b*S_+ss)*ild + c];
    }
    acc = silu_(acc);
  }
  out[(size_t)r*old_ + c] = acc;
}

// ---------------- headwise 4x4 block projections q,k,v ----------------
__global__ __launch_bounds__(256) void k_headwise(
  const float* __restrict__ xc, const float* __restrict__ xm, int xmld,
  const float* __restrict__ wq, const float* __restrict__ wk, const float* __restrict__ wv,
  float* __restrict__ q, float* __restrict__ k, float* __restrict__ v)
{
  int i=blockIdx.x*256+threadIdx.x;
  int r=i/I_, c=i%I_;
  if(r>=NP_) return;
  size_t oi=(size_t)r*I_+c;
  if(r>=NROW){ q[oi]=0.f; k[oi]=0.f; v[oi]=0.f; return; }
  int n=c>>2, o=c&3;
  const float* xcr = xc + (size_t)r*I_ + n*4;
  const float* xmr = xm + (size_t)r*xmld + n*4;
  float aq=0.f, ak=0.f, av=0.f;
  #pragma unroll
  for(int d=0;d<4;d++){
    float xcv=xcr[d], xmv=xmr[d];
    aq += xcv*wq[(n*4+o)*4+d];
    ak += xcv*wk[(n*4+o)*4+d];
    av += xmv*wv[(n*4+o)*4+d];
  }
  q[oi]=aq; k[oi]=ak; v[oi]=av;
}

// ---------------- ig/fg gates ----------------
__global__ __launch_bounds__(256) void k_igfg(
  const float* __restrict__ q, const float* __restrict__ k, const float* __restrict__ v,
  const float* __restrict__ wig, const float* __restrict__ big,
  const float* __restrict__ wfg, const float* __restrict__ bfg,
  float* __restrict__ igb, float* __restrict__ fgb)
{
  int r=blockIdx.x;
  int wid=threadIdx.x>>6, lane=threadIdx.x&63;
  int b=r/S_, s=r%S_;
  for(int c=wid; c<8; c+=4){
    int h=c>>1; int isfg=c&1;
    const float* w = isfg? wfg : wig;
    float acc=0.f;
    for(int f=lane; f<1536; f+=64){
      float val = (f<512)? q[(size_t)r*512+f]
                : (f<1024)? k[(size_t)r*512+f-512]
                : v[(size_t)r*512+f-1024];
      acc += val*w[h*1536+f];
    }
    for(int m=32;m;m>>=1) acc+=__shfl_xor(acc,m,64);
    if(lane==0){
      if(isfg) fgb[(b*4+h)*512+s]=acc+bfg[h];
      else     igb[(b*4+h)*512+s]=acc+big[h];
    }
  }
}

// ---------------- decay prep (parallel scans): one block per bh ----------------
__global__ __launch_bounds__(256) void k_decay(
  const float* __restrict__ igb, const float* __restrict__ fgb,
  float* __restrict__ cs1, float* __restrict__ g, float* __restrict__ M)
{
  int bh = blockIdx.x; int tid = threadIdx.x;
  __shared__ float buf[512];
  __shared__ float buf2[512];
  for (int s=tid; s<512; s+=256)
    buf[s] = (s<S_) ? logsig_(fgb[bh*512+s]) : 0.f;
  __syncthreads();
  for (int off=1; off<512; off<<=1){
    int s0=tid, s1=tid+256;
    float v0 = buf[s0] + ((s0>=off)? buf[s0-off] : 0.f);
    float v1 = buf[s1] + ((s1>=off)? buf[s1-off] : 0.f);
    __syncthreads();
    buf[s0]=v0; buf[s1]=v1;
    __syncthreads();
  }
  for (int s=tid; s<512; s+=256){
    float c = buf[s];
    if (s<S_){
      cs1[bh*512+s]=c;
      float gv = igb[bh*512+s]-c;
      g[bh*512+s]=gv;
      buf2[s]=gv;
    } else buf2[s] = -3.4e38f;
  }
  __syncthreads();
  for (int off=1; off<512; off<<=1){
    int s0=tid, s1=tid+256;
    float v0 = fmaxf(buf2[s0], (s0>=off)? buf2[s0-off] : -3.4e38f);
    float v1 = fmaxf(buf2[s1], (s1>=off)? buf2[s1-off] : -3.4e38f);
    __syncthreads();
    buf2[s0]=v0; buf2[s1]=v1;
    __syncthreads();
  }
  for (int s=tid; s<S_; s+=256) M[bh*512+s] = buf2[s];
}

// ---------------- tiled attention ----------------
#define TQ 32
#define TS 32
__global__ __launch_bounds__(256) void k_attn(
  const float* __restrict__ q, const float* __restrict__ k, const float* __restrict__ v,
  const float* __restrict__ cs1, const float* __restrict__ g, const float* __restrict__ M,
  const float* __restrict__ onw, float* __restrict__ hflat)
{
  __shared__ __align__(16) float qs[TQ][132];
  __shared__ __align__(16) float ks[TS][132];
  __shared__ __align__(16) float vs[TS][128];
  __shared__ float Sw[TQ][33];
  __shared__ float MtS[TQ], cssS[TQ], lsumS[TQ], gsS[TS];
  int tq = blockIdx.x, bh = blockIdx.y;
  int b = bh>>2, h = bh&3;
  int tid = threadIdx.x;
  int i = tid>>4, j = tid&15;
  int t0 = tq*TQ;
  {
    int row = tid>>3, c4 = (tid&7)*4;
    const float4* src = (const float4*)(q + (size_t)(b*S_ + t0 + row)*512 + h*128);
    float4* dst = (float4*)&qs[row][0];
    #pragma unroll
    for(int c=0;c<4;c++) dst[c4+c] = src[c4+c];
  }
  if (tid < TQ){
    int t = t0 + tid; int tc = (t<S_)? t : (S_-1);
    MtS[tid]  = M[bh*512 + tc];
    cssS[tid] = cs1[bh*512 + tc];
    lsumS[tid]= 0.f;
  }
  float o[2][8] = {};
  int t1 = min(t0+TQ, S_);
  int nst = (t1 + TS - 1)/TS;
  const float sc = 0.08838834764831843f;
  for (int st=0; st<nst; ++st){
    int s0 = st*TS;
    __syncthreads();
    {
      int row = tid>>3, c4 = (tid&7)*4;
      const float4* srck = (const float4*)(k + (size_t)(b*S_ + s0 + row)*512 + h*128);
      const float4* srcv = (const float4*)(v + (size_t)(b*S_ + s0 + row)*512 + h*128);
      float4* dk = (float4*)&ks[row][0];
      float4* dv = (float4*)&vs[row][0];
      #pragma unroll
      for(int c=0;c<4;c++){ dk[c4+c]=srck[c4+c]; dv[c4+c]=srcv[c4+c]; }
      if (tid < TS) gsS[tid] = g[bh*512 + s0 + tid];
    }
    __syncthreads();
    float a00=0,a01=0,a10=0,a11=0;
    {
      const float4* q0 = (const float4*)&qs[i*2][0];
      const float4* q1 = (const float4*)&qs[i*2+1][0];
      const float4* k0 = (const float4*)&ks[j][0];
      const float4* k1 = (const float4*)&ks[j+16][0];
      #pragma unroll
      for(int d4=0; d4<32; ++d4){
        float4 qa=q0[d4], qb=q1[d4], ka=k0[d4], kb=k1[d4];
        a00 += qa.x*ka.x+qa.y*ka.y+qa.z*ka.z+qa.w*ka.w;
        a01 += qa.x*kb.x+qa.y*kb.y+qa.z*kb.z+qa.w*kb.w;
        a10 += qb.x*ka.x+qb.y*ka.y+qb.z*ka.z+qb.w*ka.w;
        a11 += qb.x*kb.x+qb.y*kb.y+qb.z*kb.z+qb.w*kb.w;
      }
    }
    int tA = t0 + i*2, tB = tA+1;
    int sA = s0 + j,   sB = sA + 16;
    float gA = gsS[j], gB = gsS[j+16];
    float mA = MtS[i*2], mB = MtS[i*2+1];
    float w00 = (sA<=tA)? a00*sc*expneg_(gA-mA) : 0.f;
    float w01 = (sB<=tA)? a01*sc*expneg_(gB-mA) : 0.f;
    float w10 = (sA<=tB)? a10*sc*expneg_(gA-mB) : 0.f;
    float w11 = (sB<=tB)? a11*sc*expneg_(gB-mB) : 0.f;
    float r0 = w00+w01, r1 = w10+w11;
    #pragma unroll
    for(int msk=1; msk<16; msk<<=1){ r0 += __shfl_xor(r0,msk,16); r1 += __shfl_xor(r1,msk,16); }
    if (j==0){ lsumS[i*2] += r0; lsumS[i*2+1] += r1; }
    Sw[i*2][j]     = w00; Sw[i*2][j+16]   = w01;
    Sw[i*2+1][j]   = w10; Sw[i*2+1][j+16] = w11;
    __syncthreads();
    #pragma unroll 8
    for(int s=0;s<TS;s++){
      float w0 = Sw[i*2][s], w1 = Sw[i*2+1][s];
      float4 v0 = *(const float4*)&vs[s][j*4];
      float4 v1 = *(const float4*)&vs[s][64+j*4];
      o[0][0]+=w0*v0.x; o[0][1]+=w0*v0.y; o[0][2]+=w0*v0.z; o[0][3]+=w0*v0.w;
      o[0][4]+=w0*v1.x; o[0][5]+=w0*v1.y; o[0][6]+=w0*v1.z; o[0][7]+=w0*v1.w;
      o[1][0]+=w1*v0.x; o[1][1]+=w1*v0.y; o[1][2]+=w1*v0.z; o[1][3]+=w1*v0.w;
      o[1][4]+=w1*v1.x; o[1][5]+=w1*v1.y; o[1][6]+=w1*v1.z; o[1][7]+=w1*v1.w;
    }
  }
  __syncthreads();
  #pragma unroll
  for(int r=0;r<2;r++){
    int tl = i*2+r;
    int t = t0 + tl;
    float maxD = cssS[tl] + MtS[tl];
    float norm = fmaxf(fabsf(lsumS[tl]), expclamp_(-maxD));
    float scale = rcp_(norm+1e-6f);
    float sum=0.f;
    #pragma unroll
    for(int d=0;d<8;d++){ o[r][d]*=scale; sum+=o[r][d]; }
    #pragma unroll
    for(int msk=1; msk<16; msk<<=1) sum += __shfl_xor(sum,msk,16);
    float mu = sum*(1.f/128.f);
    float var=0.f;
    #pragma unroll
    for(int d=0;d<8;d++){ float dd=o[r][d]-mu; var+=dd*dd; }
    #pragma unroll
    for(int msk=1; msk<16; msk<<=1) var += __shfl_xor(var,msk,16);
    float rs = rsqrtf(var*(1.f/128.f)+EPS_);
    if (t < S_){
      float* dst = hflat + (size_t)(b*S_+t)*1024 + h*128;
      #pragma unroll
      for(int c=0;c<4;c++) dst[j*4+c]    = (o[r][c]  -mu)*rs*onw[h*128+j*4+c];
      #pragma unroll
      for(int c=0;c<4;c++) dst[64+j*4+c] = (o[r][4+c]-mu)*rs*onw[h*128+64+j*4+c];
    }
  }
}

// ---------------- hout = (hflat + skip*xc) * silu(z) -> bf16 ----------------
__global__ __launch_bounds__(256) void k_hout(
  const float* __restrict__ A, const float* __restrict__ xc, const float* __restrict__ skip,
  bf16* __restrict__ out16)
{
  int i=blockIdx.x*256+threadIdx.x;
  int r=i/512, c=i%512;
  float hf=A[(size_t)r*1024+c];
  float z =A[(size_t)r*1024+512+c];
  out16[(size_t)r*512+c] = __float2bfloat16((hf + skip[c]*xc[(size_t)r*512+c]) * silu_(z));
}

// ---------------- wx = gate pre-activations, scan layout [bn][s][g*64+e] ----------------
__global__ __launch_bounds__(256) void k_wx(
  const float* __restrict__ h, const float* __restrict__ hc,
  const float* __restrict__ gw, const float* __restrict__ gb,
  float* __restrict__ wx)
{
  __shared__ float hs[256], hcs[256];
  int r=blockIdx.x; int t=threadIdx.x;
  hs[t]=h[(size_t)r*256+t]; hcs[t]=hc[(size_t)r*256+t];
  __syncthreads();
  int b=r/S_, s=r%S_;
  int n=t>>6, e=t&63;
  #pragma unroll
  for(int gg=0; gg<4; gg++){
    const float* src = (gg<2? hcs: hs) + n*64;
    const float* wp = gw + (size_t)(((gg*4+n)*64+e))*64;
    float acc=gb[(gg*4+n)*64+e];
    #pragma unroll 8
    for(int d=0;d<64;d++) acc+=src[d]*wp[d];
    wx[((size_t)(b*4+n)*512 + s)*256 + gg*64 + e]=acc;
  }
}

// ---------------- sLSTM scan: readlane matvec + chunked LDS y-buffer ----------------
#define YCH 32
__global__ __launch_bounds__(256,1) void k_scan(
  const float* __restrict__ wx, const float* __restrict__ rw, float* __restrict__ y_out)
{
  int bn = blockIdx.x; int b = bn>>2, n = bn&3;
  int tid = threadIdx.x; int g = tid>>6, e = tid&63;
  float W[64];
  #pragma unroll
  for(int d=0;d<64;d++) W[d]=rw[(size_t)(((g*4+n)*64+d))*64 + e];
  __shared__ float rawS[2][256];
  __shared__ __align__(16) float wxS[2][YCH*256];
  __shared__ float ybuf[YCH*64];
  const float* wxBase = wx + (size_t)bn*512*256;
  { // stage chunk 0
    const float4* src=(const float4*)wxBase;
    float4* dst=(float4*)&wxS[0][0];
    #pragma unroll
    for(int j=0;j<8;j++) dst[j*256+tid]=src[j*256+tid];
  }
  float c=0.f, nn=0.f, m=0.f, yreg=0.f;
  __syncthreads();
  for (int s=0; s<S_; ++s){
    int sl = s & (YCH-1);
    int p  = s & 1;
    float wxv = wxS[(s>>5)&1][sl*256 + tid];
    float a0=0.f,a1=0.f,a2=0.f,a3=0.f;
    #pragma unroll
    for(int d=0; d<64; d+=4){
      a0 += rdlane_(yreg,d  )*W[d  ];
      a1 += rdlane_(yreg,d+1)*W[d+1];
      a2 += rdlane_(yreg,d+2)*W[d+2];
      a3 += rdlane_(yreg,d+3)*W[d+3];
    }
    rawS[p][tid] = wxv + ((a0+a1)+(a2+a3));
    __syncthreads();
    float iraw=rawS[p][e], fraw=rawS[p][64+e], zraw=rawS[p][128+e], oraw=rawS[p][192+e];
    float lfm = m + logsig_(fraw);
    float mnew = fmaxf(iraw, lfm);
    float ig = expneg_(iraw-mnew), fg=expneg_(lfm-mnew);
    c  = fg*c  + ig*tanh_(zraw);
    nn = fmaxf(fg*nn + ig, 1e-30f);
    float y = sig_(oraw) * c * rcp_(nn);
    m = mnew;
    yreg = y;
    if (g==0) ybuf[sl*64+e] = y;
    if (sl==YCH-1 || s==S_-1){
      __syncthreads();                    // make wave-0's ybuf writes visible
      int s0 = s-sl;
      int cnt = (sl+1)*64;
      for(int idx=tid; idx<cnt; idx+=256){
        int ss=s0+(idx>>6), ee=idx&63;
        y_out[((size_t)b*S_+ss)*256 + n*64 + ee] = ybuf[idx];
      }
      int nch=(s>>5)+1;
      if (nch<16){
        const float4* src=(const float4*)(wxBase+(size_t)nch*YCH*256);
        float4* dst=(float4*)&wxS[nch&1][0];
        #pragma unroll
        for(int j=0;j<8;j++) dst[j*256+tid]=src[j*256+tid];
      }
      __syncthreads();                    // WAR-protect ybuf + publish next wx chunk
    }
  }
}

// ---------------- yn-add + fused LN2 -> bf16 ----------------
__global__ __launch_bounds__(256) void k_ynadd_ln2(
  const float* __restrict__ y, const float* __restrict__ gn,
  float* __restrict__ x, const float* __restrict__ ln2w, bf16* __restrict__ h16)
{
  __shared__ float red[256];
  int r=blockIdx.x, t=threadIdx.x;
  float xv = x[(size_t)r*256+t];
  if (r < NROW){
    float v=y[(size_t)r*256+t];
    float s=v;
    for(int m=32;m;m>>=1) s+=__shfl_xor(s,m,64);
    float mu=s*(1.f/64.f);
    float d=v-mu;
    float q=d*d;
    for(int m=32;m;m>>=1) q+=__shfl_xor(q,m,64);
    float var=q*(1.f/64.f);
    xv += d*rsqrtf(var+EPS_)*gn[t];
    x[(size_t)r*256+t]=xv;
  }
  red[t]=xv; __syncthreads();
  for(int s=128;s>0;s>>=1){ if(t<s) red[t]+=red[t+s]; __syncthreads(); }
  float mu2=red[0]*(1.f/E_); __syncthreads();
  float dd=xv-mu2;
  red[t]=dd*dd; __syncthreads();
  for(int s=128;s>0;s>>=1){ if(t<s) red[t]+=red[t+s]; __syncthreads(); }
  float var2=red[0]*(1.f/E_);
  h16[(size_t)r*256+t]=__float2bfloat16(dd*rsqrtf(var2+EPS_)*ln2w[t]);
}

// ---------------- ffn gate: relu(gate)*upf -> bf16 ----------------
__global__ __launch_bounds__(256) void k_ffmul(const float* __restrict__ ffu, bf16* __restrict__ out)
{
  int i=blockIdx.x*256+threadIdx.x;
  int r=i/384, j=i%384;
  out[(size_t)r*384+j] = __float2bfloat16(fmaxf(ffu[(size_t)r*768+j],0.f)*ffu[(size_t)r*768+384+j]);
}

// ---------------- fused postnorm-LN + cq build -> bf16 ----------------
__global__ __launch_bounds__(256) void k_cq_ln(
  const float* __restrict__ x, const float* __restrict__ pw,
  const float* __restrict__ qe, const float* __restrict__ pide, const int* __restrict__ tgt,
  bf16* __restrict__ cq)
{
  __shared__ float red[256];
  int r=blockIdx.x, t=threadIdx.x;
  float v = x[(size_t)r*256+t];
  red[t]=v; __syncthreads();
  for(int s=128;s>0;s>>=1){ if(t<s) red[t]+=red[t+s]; __syncthreads(); }
  float mu=red[0]*(1.f/E_); __syncthreads();
  float d=v-mu;
  red[t]=d*d; __syncthreads();
  for(int s=128;s>0;s>>=1){ if(t<s) red[t]+=red[t+s]; __syncthreads(); }
  float var=red[0]*(1.f/E_);
  float dv = d*rsqrtf(var+EPS_)*pw[t];
  float pe=pide[r]; int tg=tgt[r];
  size_t base=(size_t)r*1024;
  cq[base+t]=__float2bfloat16(dv-pe);
  cq[base+256+t]=__float2bfloat16(qe[(size_t)r*256+t]);
  cq[base+512+t]=__float2bfloat16((tg==1)? dv:0.f);
  cq[base+768+t]=__float2bfloat16((tg==0)? dv:0.f);
}

// ---------------- final: selected logit + sigmoid ----------------
__global__ __launch_bounds__(256) void k_final(
  const float* __restrict__ o2, const float* __restrict__ w3, const float* __restrict__ b3,
  const int* __restrict__ qsh, float* __restrict__ out)
{
  __shared__ float red[256];
  int r=blockIdx.x, t=threadIdx.x;
  int qi=qsh[r];
  float p=o2[(size_t)r*256+t]*w3[(size_t)qi*256+t];
  red[t]=p; __syncthreads();
  for(int s=128;s>0;s>>=1){ if(t<s) red[t]+=red[t+s]; __syncthreads(); }
  if(t==0) out[r]=sig_(red[0]+b3[qi]);
}

// ---------------- launch ----------------
extern "C" void kernel_launch(void* const* d_in, const int* in_sizes, int n_in,
                              void* d_out, int out_size, void* d_ws, size_t ws_size,
                              hipStream_t stream) {
  const int* questions = (const int*)d_in[0];
  const int* responses = (const int*)d_in[1];
  const int* skills    = (const int*)d_in[2];
  const float* q_embed       = (const float*)d_in[4];
  const float* qa_embed      = (const float*)d_in[5];
  const float* q_embed_diff  = (const float*)d_in[6];
  const float* qa_embed_diff = (const float*)d_in[7];
  const float* difficult_param=(const float*)d_in[8];
  const float* ln0_w   = (const float*)d_in[9];
  const float* m_up_w  = (const float*)d_in[10];
  const float* m_up_b  = (const float*)d_in[11];
  const float* m_conv_w= (const float*)d_in[12];
  const float* m_conv_b= (const float*)d_in[13];
  const float* m_q_w   = (const float*)d_in[14];
  const float* m_k_w   = (const float*)d_in[15];
  const float* m_v_w   = (const float*)d_in[16];
  const float* m_ig_w  = (const float*)d_in[17];
  const float* m_ig_b  = (const float*)d_in[18];
  const float* m_fg_w  = (const float*)d_in[19];
  const float* m_fg_b  = (const float*)d_in[20];
  const float* m_outnorm_w=(const float*)d_in[21];
  const float* m_skip  = (const float*)d_in[22];
  const float* m_down_w= (const float*)d_in[23];
  const float* m_down_b= (const float*)d_in[24];
  const float* ln1_w   = (const float*)d_in[25];
  const float* s_conv_w= (const float*)d_in[26];
  const float* s_conv_b= (const float*)d_in[27];
  const float* s_gate_w= (const float*)d_in[28];
  const float* s_rec_w = (const float*)d_in[29];
  const float* s_bias  = (const float*)d_in[30];
  const float* s_gn_w  = (const float*)d_in[31];
  const float* ln2_w   = (const float*)d_in[32];
  const float* ffn_up_w= (const float*)d_in[33];
  const float* ffn_up_b= (const float*)d_in[34];
  const float* ffn_down_w=(const float*)d_in[35];
  const float* ffn_down_b=(const float*)d_in[36];
  const float* postnorm_w=(const float*)d_in[37];
  const float* out_w1  = (const float*)d_in[38];
  const float* out_b1  = (const float*)d_in[39];
  const float* out_w2  = (const float*)d_in[40];
  const float* out_b2  = (const float*)d_in[41];
  const float* out_w3  = (const float*)d_in[42];
  const float* out_b3  = (const float*)d_in[43];

  float* ws = (float*)d_ws;
  const size_t R = (size_t)NP_*256;
  float* x    = ws;
  float* qe   = ws + R;
  float* h    = ws + 2*R;
  float* t256 = ws + 3*R;        // early: split-bf16 LN0 output (h_hi/h_lo); late: out_w2 result
  float* A    = ws + 4*R;        // NP x 1024 ; also scan-layout wx
  float* Bb   = ws + 8*R;        // NP x 512
  float* Cb   = ws + 10*R;       // NP x 512  (q; later y_out; later b16)
  float* Db   = ws + 12*R;       // NP x 512  (k; later hout16 / ffg16)
  float* Eb   = ws + 14*R;       // NP x 512  (v; later cq16)
  float* pide = ws + 16*R;
  int*   tgt  = (int*)(ws + 16*R + NP_);
  int*   qsh  = (int*)(ws + 16*R + 2*NP_);
  float* igb  = ws + 16*R + 3*NP_;
  float* fgb  = igb + 64*512;
  float* cs1  = fgb + 64*512;
  float* gdec = cs1 + 64*512;
  float* Mrun = gdec + 64*512;
  bf16* wpool = (bf16*)(Mrun + 64*512);
  bf16* m_down_w16  = wpool;
  bf16* ffn_up_w16  = m_down_w16 + 256*512;
  bf16* ffn_down_w16= ffn_up_w16 + 768*256;
  bf16* out_w1_16   = ffn_down_w16 + 256*384;
  bf16* out_w2_16   = out_w1_16 + 512*1024;
  bf16* h16         = out_w2_16 + 256*512;
  bf16* m_up_whi    = h16 + (size_t)NP_*256;     // 1024*256
  bf16* m_up_wlo    = m_up_whi + 1024*256;       // 1024*256
  bf16* hout16 = (bf16*)Db;
  bf16* ffg16  = (bf16*)Db;
  bf16* cq16   = (bf16*)Eb;
  bf16* b16    = (bf16*)Cb;
  bf16* h_hi   = (bf16*)t256;                    // NP*256
  bf16* h_lo   = h_hi + (size_t)NP_*256;         // NP*256 (fits in t256's R floats)

  // ---- one-time weight conversions ----
  k_cvt16<<<(256*512+255)/256,256,0,stream>>>(m_down_w,  m_down_w16,  256*512);
  k_cvt16<<<(768*256+255)/256,256,0,stream>>>(ffn_up_w,  ffn_up_w16,  768*256);
  k_cvt16<<<(256*384+255)/256,256,0,stream>>>(ffn_down_w,ffn_down_w16,256*384);
  k_cvt16<<<(512*1024+255)/256,256,0,stream>>>(out_w1,   out_w1_16,   512*1024);
  k_cvt16<<<(256*512+255)/256,256,0,stream>>>(out_w2,    out_w2_16,   256*512);
  k_cvtsplit<<<(1024*256+255)/256,256,0,stream>>>(m_up_w, m_up_whi, m_up_wlo, 1024*256);

  // ---- embeddings (+LN0 -> split bf16) ----
  k_embed<<<NP_,256,0,stream>>>(questions,responses,skills,q_embed,qa_embed,
      q_embed_diff,qa_embed_diff,difficult_param, ln0_w, x,qe, h_hi,h_lo, pide,tgt,qsh);
  // ---- block M ----
  k_gemm16s<<<dim3(1024/64,NP_/64),256,0,stream>>>(h_hi,h_lo, m_up_whi,m_up_wlo, m_up_b, A, 1024,256);
  k_conv_silu<<<(NP_*512)/256,256,0,stream>>>(A,1024, m_conv_w,m_conv_b, Bb,512,512);
  k_headwise<<<(NP_*512)/256,256,0,stream>>>(Bb, A,1024, m_q_w,m_k_w,m_v_w, Cb,Db,Eb);
  k_igfg<<<NROW,256,0,stream>>>(Cb,Db,Eb, m_ig_w,m_ig_b,m_fg_w,m_fg_b, igb,fgb);
  k_decay<<<64,256,0,stream>>>(igb,fgb, cs1,gdec,Mrun);
  k_attn<<<dim3((S_+TQ-1)/TQ, B_*NH_),256,0,stream>>>(Cb,Db,Eb, cs1,gdec,Mrun, m_outnorm_w, A);
  k_hout<<<(NP_*512)/256,256,0,stream>>>(A, Bb, m_skip, hout16);
  k_gemm16<<<dim3(256/64,NP_/64),256,0,stream>>>(hout16, m_down_w16, m_down_b, x, x, (bf16*)nullptr, 256,512,0);
  // ---- block S ----
  k_ln<<<NP_,256,0,stream>>>(x, ln1_w, h);
  k_conv_silu<<<(NP_*256)/256,256,0,stream>>>(h,256, s_conv_w,s_conv_b, Bb,256,256);
  k_wx<<<NROW,256,0,stream>>>(h, Bb, s_gate_w, s_bias, A);
  k_scan<<<64,256,0,stream>>>(A, s_rec_w, Cb);
  k_ynadd_ln2<<<NP_,256,0,stream>>>(Cb, s_gn_w, x, ln2_w, h16);
  // ---- FFN ----
  k_gemm16<<<dim3(768/64,NP_/64),256,0,stream>>>(h16, ffn_up_w16, ffn_up_b, (const float*)nullptr, A, (bf16*)nullptr, 768,256,0);
  k_ffmul<<<(NP_*384)/256,256,0,stream>>>(A, ffg16);
  k_gemm16<<<dim3(256/64,NP_/64),256,0,stream>>>(ffg16, ffn_down_w16, ffn_down_b, x, x, (bf16*)nullptr, 256,384,0);
  // ---- output head ----
  k_cq_ln<<<NP_,256,0,stream>>>(x, postnorm_w, qe, pide, tgt, cq16);
  k_gemm16<<<dim3(512/64,NP_/64),256,0,stream>>>(cq16, out_w1_16, out_b1, (const float*)nullptr, (float*)nullptr, b16, 512,1024,1);
  k_gemm16<<<dim3(256/64,NP_/64),256,0,stream>>>(b16, out_w2_16, out_b2, (const float*)nullptr, t256, (bf16*)nullptr, 256,512,1);
  k_final<<<NROW,256,0,stream>>>(t256, out_w3, out_b3, qsh, (float*)d_out);
}

// Round 14
// 1063.826 us; speedup vs baseline: 1.4615x; 1.2832x over previous
//
#include <hip/hip_runtime.h>
#include <hip/hip_bf16.h>

// ---------------- constants ----------------
#define B_    16
#define SL_   512
#define S_    511
#define E_    256
#define NH_   4
#define I_    512
#define DHM_  128
#define DHS_  64
#define F_    384
#define NP_   8192               // padded row count (multiple of 64)
#define NROW  (B_*S_)            // 8176 real rows
#define EPS_  1e-5f

typedef __hip_bfloat16 bf16;
typedef __bf16 bf16x8v __attribute__((ext_vector_type(8)));
typedef float  f32x4v  __attribute__((ext_vector_type(4)));

__device__ __forceinline__ float rcp_(float x){ return __builtin_amdgcn_rcpf(x); }
__device__ __forceinline__ float sig_(float x){ return rcp_(1.f+__expf(-x)); }
__device__ __forceinline__ float silu_(float x){ return x*sig_(x); }
__device__ __forceinline__ float logsig_(float x){ return fminf(x,0.f) - __logf(1.f + __expf(-fabsf(x))); }
__device__ __forceinline__ float expneg_(float x){ return __expf(fminf(x,0.f)); }
__device__ __forceinline__ float expclamp_(float x){ return __expf(fminf(fmaxf(x,-80.f),80.f)); }
__device__ __forceinline__ float tanh_(float x){ return 1.f - 2.f*rcp_(__expf(2.f*x)+1.f); }
__device__ __forceinline__ float rdlane_(float v, int l){
  return __uint_as_float(__builtin_amdgcn_readlane(__float_as_uint(v), (unsigned)l));
}

// ---------------- f32 -> bf16 weight conversion ----------------
__global__ __launch_bounds__(256) void k_cvt16(const float* __restrict__ src, bf16* __restrict__ dst, int n){
  int i=blockIdx.x*256+threadIdx.x;
  if(i<n) dst[i]=__float2bfloat16(src[i]);
}
// ---------------- f32 -> split bf16 (hi+lo) conversion ----------------
__global__ __launch_bounds__(256) void k_cvtsplit(const float* __restrict__ src,
  bf16* __restrict__ hi, bf16* __restrict__ lo, int n){
  int i=blockIdx.x*256+threadIdx.x;
  if(i<n){
    float v=src[i];
    bf16 h=__float2bfloat16(v);
    hi[i]=h;
    lo[i]=__float2bfloat16(v-__bfloat162float(h));
  }
}
// ---------------- transpose s_gate_w's inner 64x64 blocks: dst[blk][d][e]=src[blk][e][d] ----------------
__global__ __launch_bounds__(256) void k_wtrans(const float* __restrict__ src, float* __restrict__ dst){
  int i = blockIdx.x*256+threadIdx.x;   // over 16*64*64
  int blk = i>>12;
  int d = (i>>6)&63;
  int e = i&63;
  dst[(size_t)(blk*64+d)*64+e] = src[(size_t)(blk*64+e)*64+d];
}

// ---------------- embedding gather + fused LN0 -> split bf16 ----------------
__global__ __launch_bounds__(256) void k_embed(
  const int* __restrict__ questions, const int* __restrict__ responses, const int* __restrict__ skills,
  const float* __restrict__ q_embed, const float* __restrict__ qa_embed,
  const float* __restrict__ q_embed_diff, const float* __restrict__ qa_embed_diff,
  const float* __restrict__ difficult_param, const float* __restrict__ ln0w,
  float* __restrict__ x, float* __restrict__ qe,
  bf16* __restrict__ h_hi, bf16* __restrict__ h_lo,
  float* __restrict__ pide, int* __restrict__ tgt, int* __restrict__ qsh)
{
  __shared__ float red[256];
  int r = blockIdx.x; int e = threadIdx.x;
  float xa = 0.f;
  if (r < NROW){
    int b = r / S_, s = r % S_;
    int pid  = questions[b*SL_+s];
    int qd   = skills[b*SL_+s];
    int resp = responses[b*SL_+s];
    int t    = (resp > -1) ? resp : 0;
    float pe = difficult_param[pid];
    float q0 = q_embed[qd*E_+e];
    xa = q0 + qa_embed[t*E_+e] + pe*qa_embed_diff[t*E_+e];
    float qn = q0 + pe*q_embed_diff[qd*E_+e];
    x[(size_t)r*E_+e]=xa; qe[(size_t)r*E_+e]=qn;
    if (e==0){ pide[r]=pe; tgt[r]=t; qsh[r]=skills[b*SL_+s+1]; }
  } else {
    x[(size_t)r*E_+e]=0.f; qe[(size_t)r*E_+e]=0.f;
    if (e==0){ pide[r]=0.f; tgt[r]=-7; qsh[r]=0; }
  }
  red[e]=xa; __syncthreads();
  for(int s2=128;s2>0;s2>>=1){ if(e<s2) red[e]+=red[e+s2]; __syncthreads(); }
  float mu = red[0]*(1.f/E_); __syncthreads();
  float d = xa-mu;
  red[e]=d*d; __syncthreads();
  for(int s2=128;s2>0;s2>>=1){ if(e<s2) red[e]+=red[e+s2]; __syncthreads(); }
  float var = red[0]*(1.f/E_);
  float o = d*rsqrtf(var+EPS_)*ln0w[e];
  bf16 hv = __float2bfloat16(o);
  h_hi[(size_t)r*E_+e] = hv;
  h_lo[(size_t)r*E_+e] = __float2bfloat16(o-__bfloat162float(hv));
}

// ---------------- layernorm over E=256 (used for ln1) ----------------
__global__ __launch_bounds__(256) void k_ln(
  const float* __restrict__ in, const float* __restrict__ w, float* __restrict__ out)
{
  __shared__ float red[256];
  int r = blockIdx.x, t = threadIdx.x;
  float v = in[(size_t)r*E_+t];
  red[t]=v; __syncthreads();
  for(int s=128;s>0;s>>=1){ if(t<s) red[t]+=red[t+s]; __syncthreads(); }
  float mu = red[0]*(1.f/E_); __syncthreads();
  float d = v-mu;
  red[t]=d*d; __syncthreads();
  for(int s=128;s>0;s>>=1){ if(t<s) red[t]+=red[t+s]; __syncthreads(); }
  float var = red[0]*(1.f/E_);
  out[(size_t)r*E_+t] = d*rsqrtf(var+EPS_)*w[t];
}

// ---------------- split-bf16 MFMA GEMM: C = (Ah+Al)(Bh+Bl)^T + bias (drop lo*lo) ----------------
__global__ __launch_bounds__(256) void k_gemm16s(
  const bf16* __restrict__ Ah, const bf16* __restrict__ Al,
  const bf16* __restrict__ Bh, const bf16* __restrict__ Bl,
  const float* __restrict__ bias, float* __restrict__ C, int M, int K)
{
  int tid=threadIdx.x;
  int wave=tid>>6, lane=tid&63;
  int wr=wave>>1, wc=wave&1;
  int row0=blockIdx.y*64 + wr*32;
  int col0=blockIdx.x*64 + wc*32;
  int lrow = lane&15, lq = lane>>4;
  f32x4v acc[2][2] = {};
  size_t aoff = (size_t)(row0+lrow)*K + lq*8;
  size_t boff = (size_t)(col0+lrow)*K + lq*8;
  for(int k0=0;k0<K;k0+=32){
    bf16x8v ah0=*(const bf16x8v*)(Ah+aoff+k0), ah1=*(const bf16x8v*)(Ah+aoff+(size_t)16*K+k0);
    bf16x8v al0=*(const bf16x8v*)(Al+aoff+k0), al1=*(const bf16x8v*)(Al+aoff+(size_t)16*K+k0);
    bf16x8v bh0=*(const bf16x8v*)(Bh+boff+k0), bh1=*(const bf16x8v*)(Bh+boff+(size_t)16*K+k0);
    bf16x8v bl0=*(const bf16x8v*)(Bl+boff+k0), bl1=*(const bf16x8v*)(Bl+boff+(size_t)16*K+k0);
    acc[0][0]=__builtin_amdgcn_mfma_f32_16x16x32_bf16(ah0,bh0,acc[0][0],0,0,0);
    acc[0][1]=__builtin_amdgcn_mfma_f32_16x16x32_bf16(ah0,bh1,acc[0][1],0,0,0);
    acc[1][0]=__builtin_amdgcn_mfma_f32_16x16x32_bf16(ah1,bh0,acc[1][0],0,0,0);
    acc[1][1]=__builtin_amdgcn_mfma_f32_16x16x32_bf16(ah1,bh1,acc[1][1],0,0,0);
    acc[0][0]=__builtin_amdgcn_mfma_f32_16x16x32_bf16(ah0,bl0,acc[0][0],0,0,0);
    acc[0][1]=__builtin_amdgcn_mfma_f32_16x16x32_bf16(ah0,bl1,acc[0][1],0,0,0);
    acc[1][0]=__builtin_amdgcn_mfma_f32_16x16x32_bf16(ah1,bl0,acc[1][0],0,0,0);
    acc[1][1]=__builtin_amdgcn_mfma_f32_16x16x32_bf16(ah1,bl1,acc[1][1],0,0,0);
    acc[0][0]=__builtin_amdgcn_mfma_f32_16x16x32_bf16(al0,bh0,acc[0][0],0,0,0);
    acc[0][1]=__builtin_amdgcn_mfma_f32_16x16x32_bf16(al0,bh1,acc[0][1],0,0,0);
    acc[1][0]=__builtin_amdgcn_mfma_f32_16x16x32_bf16(al1,bh0,acc[1][0],0,0,0);
    acc[1][1]=__builtin_amdgcn_mfma_f32_16x16x32_bf16(al1,bh1,acc[1][1],0,0,0);
  }
  #pragma unroll
  for(int mi=0;mi<2;mi++){
    #pragma unroll
    for(int ni=0;ni<2;ni++){
      #pragma unroll
      for(int r=0;r<4;r++){
        int row=row0+mi*16+lq*4+r;
        int col=col0+ni*16+lrow;
        C[(size_t)row*M+col]=acc[mi][ni][r] + bias[col];
      }
    }
  }
}

// ---------------- bf16 MFMA GEMM (+ optional residual) ----------------
__global__ __launch_bounds__(256) void k_gemm16(
  const bf16* __restrict__ A, const bf16* __restrict__ Bw,
  const float* __restrict__ bias, const float* __restrict__ resid,
  float* __restrict__ C, bf16* __restrict__ C16,
  int M, int K, int relu)
{
  int tid=threadIdx.x;
  int wave=tid>>6, lane=tid&63;
  int wr=wave>>1, wc=wave&1;
  int row0=blockIdx.y*64 + wr*32;
  int col0=blockIdx.x*64 + wc*32;
  int lrow = lane&15, lq = lane>>4;
  f32x4v acc[2][2] = {};
  const bf16* Abase = A  + (size_t)(row0+lrow)*K + lq*8;
  const bf16* Bbase = Bw + (size_t)(col0+lrow)*K + lq*8;
  for(int k0=0;k0<K;k0+=32){
    bf16x8v a0 = *(const bf16x8v*)(Abase + k0);
    bf16x8v a1 = *(const bf16x8v*)(Abase + (size_t)16*K + k0);
    bf16x8v b0 = *(const bf16x8v*)(Bbase + k0);
    bf16x8v b1 = *(const bf16x8v*)(Bbase + (size_t)16*K + k0);
    acc[0][0]=__builtin_amdgcn_mfma_f32_16x16x32_bf16(a0,b0,acc[0][0],0,0,0);
    acc[0][1]=__builtin_amdgcn_mfma_f32_16x16x32_bf16(a0,b1,acc[0][1],0,0,0);
    acc[1][0]=__builtin_amdgcn_mfma_f32_16x16x32_bf16(a1,b0,acc[1][0],0,0,0);
    acc[1][1]=__builtin_amdgcn_mfma_f32_16x16x32_bf16(a1,b1,acc[1][1],0,0,0);
  }
  #pragma unroll
  for(int mi=0;mi<2;mi++){
    #pragma unroll
    for(int ni=0;ni<2;ni++){
      #pragma unroll
      for(int r=0;r<4;r++){
        int row=row0+mi*16+lq*4+r;       // C/D: col=lane&15, row=(lane>>4)*4+reg  [m89]
        int col=col0+ni*16+lrow;
        float v=acc[mi][ni][r] + (bias? bias[col]:0.f);
        if(relu) v=fmaxf(v,0.f);
        if(resid) v += resid[(size_t)row*M+col];
        if(C)   C[(size_t)row*M+col]=v;
        if(C16) C16[(size_t)row*M+col]=__float2bfloat16(v);
      }
    }
  }
}

// ---------------- causal depthwise conv K=4 + silu ----------------
__global__ __launch_bounds__(256) void k_conv_silu(
  const float* __restrict__ in, int ild, const float* __restrict__ w, const float* __restrict__ bws,
  float* __restrict__ out, int old_, int C)
{
  int i = blockIdx.x*256 + threadIdx.x;
  int r = i / C, c = i % C;
  if (r >= NP_) return;
  float acc = 0.f;
  if (r < NROW) {
    int b=r/S_, s=r%S_;
    acc = bws[c];
    #pragma unroll
    for(int j=0;j<4;j++){
      int ss=s-3+j;
      if(ss>=0) acc += w[c*4+j] * in[(size_t)(b*S_+ss)*ild + c];
    }
    acc = silu_(acc);
  }
  out[(size_t)r*old_ + c] = acc;
}

// ---------------- headwise 4x4 block projections q,k,v ----------------
__global__ __launch_bounds__(256) void k_headwise(
  const float* __restrict__ xc, const float* __restrict__ xm, int xmld,
  const float* __restrict__ wq, const float* __restrict__ wk, const float* __restrict__ wv,
  float* __restrict__ q, float* __restrict__ k, float* __restrict__ v)
{
  int i=blockIdx.x*256+threadIdx.x;
  int r=i/I_, c=i%I_;
  if(r>=NP_) return;
  size_t oi=(size_t)r*I_+c;
  if(r>=NROW){ q[oi]=0.f; k[oi]=0.f; v[oi]=0.f; return; }
  int n=c>>2, o=c&3;
  const float* xcr = xc + (size_t)r*I_ + n*4;
  const float* xmr = xm + (size_t)r*xmld + n*4;
  float aq=0.f, ak=0.f, av=0.f;
  #pragma unroll
  for(int d=0;d<4;d++){
    float xcv=xcr[d], xmv=xmr[d];
    aq += xcv*wq[(n*4+o)*4+d];
    ak += xcv*wk[(n*4+o)*4+d];
    av += xmv*wv[(n*4+o)*4+d];
  }
  q[oi]=aq; k[oi]=ak; v[oi]=av;
}

// ---------------- ig/fg gates ----------------
__global__ __launch_bounds__(256) void k_igfg(
  const float* __restrict__ q, const float* __restrict__ k, const float* __restrict__ v,
  const float* __restrict__ wig, const float* __restrict__ big,
  const float* __restrict__ wfg, const float* __restrict__ bfg,
  float* __restrict__ igb, float* __restrict__ fgb)
{
  int r=blockIdx.x;
  int wid=threadIdx.x>>6, lane=threadIdx.x&63;
  int b=r/S_, s=r%S_;
  for(int c=wid; c<8; c+=4){
    int h=c>>1; int isfg=c&1;
    const float* w = isfg? wfg : wig;
    float acc=0.f;
    for(int f=lane; f<1536; f+=64){
      float val = (f<512)? q[(size_t)r*512+f]
                : (f<1024)? k[(size_t)r*512+f-512]
                : v[(size_t)r*512+f-1024];
      acc += val*w[h*1536+f];
    }
    for(int m=32;m;m>>=1) acc+=__shfl_xor(acc,m,64);
    if(lane==0){
      if(isfg) fgb[(b*4+h)*512+s]=acc+bfg[h];
      else     igb[(b*4+h)*512+s]=acc+big[h];
    }
  }
}

// ---------------- decay prep (parallel scans): one block per bh ----------------
__global__ __launch_bounds__(256) void k_decay(
  const float* __restrict__ igb, const float* __restrict__ fgb,
  float* __restrict__ cs1, float* __restrict__ g, float* __restrict__ M)
{
  int bh = blockIdx.x; int tid = threadIdx.x;
  __shared__ float buf[512];
  __shared__ float buf2[512];
  for (int s=tid; s<512; s+=256)
    buf[s] = (s<S_) ? logsig_(fgb[bh*512+s]) : 0.f;
  __syncthreads();
  for (int off=1; off<512; off<<=1){
    int s0=tid, s1=tid+256;
    float v0 = buf[s0] + ((s0>=off)? buf[s0-off] : 0.f);
    float v1 = buf[s1] + ((s1>=off)? buf[s1-off] : 0.f);
    __syncthreads();
    buf[s0]=v0; buf[s1]=v1;
    __syncthreads();
  }
  for (int s=tid; s<512; s+=256){
    float c = buf[s];
    if (s<S_){
      cs1[bh*512+s]=c;
      float gv = igb[bh*512+s]-c;
      g[bh*512+s]=gv;
      buf2[s]=gv;
    } else buf2[s] = -3.4e38f;
  }
  __syncthreads();
  for (int off=1; off<512; off<<=1){
    int s0=tid, s1=tid+256;
    float v0 = fmaxf(buf2[s0], (s0>=off)? buf2[s0-off] : -3.4e38f);
    float v1 = fmaxf(buf2[s1], (s1>=off)? buf2[s1-off] : -3.4e38f);
    __syncthreads();
    buf2[s0]=v0; buf2[s1]=v1;
    __syncthreads();
  }
  for (int s=tid; s<S_; s+=256) M[bh*512+s] = buf2[s];
}

// ---------------- tiled attention ----------------
#define TQ 32
#define TS 32
__global__ __launch_bounds__(256) void k_attn(
  const float* __restrict__ q, const float* __restrict__ k, const float* __restrict__ v,
  const float* __restrict__ cs1, const float* __restrict__ g, const float* __restrict__ M,
  const float* __restrict__ onw, float* __restrict__ hflat)
{
  __shared__ __align__(16) float qs[TQ][132];
  __shared__ __align__(16) float ks[TS][132];
  __shared__ __align__(16) float vs[TS][128];
  __shared__ float Sw[TQ][33];
  __shared__ float MtS[TQ], cssS[TQ], lsumS[TQ], gsS[TS];
  int tq = blockIdx.x, bh = blockIdx.y;
  int b = bh>>2, h = bh&3;
  int tid = threadIdx.x;
  int i = tid>>4, j = tid&15;
  int t0 = tq*TQ;
  {
    int row = tid>>3, c4 = (tid&7)*4;
    const float4* src = (const float4*)(q + (size_t)(b*S_ + t0 + row)*512 + h*128);
    float4* dst = (float4*)&qs[row][0];
    #pragma unroll
    for(int c=0;c<4;c++) dst[c4+c] = src[c4+c];
  }
  if (tid < TQ){
    int t = t0 + tid; int tc = (t<S_)? t : (S_-1);
    MtS[tid]  = M[bh*512 + tc];
    cssS[tid] = cs1[bh*512 + tc];
    lsumS[tid]= 0.f;
  }
  float o[2][8] = {};
  int t1 = min(t0+TQ, S_);
  int nst = (t1 + TS - 1)/TS;
  const float sc = 0.08838834764831843f;
  for (int st=0; st<nst; ++st){
    int s0 = st*TS;
    __syncthreads();
    {
      int row = tid>>3, c4 = (tid&7)*4;
      const float4* srck = (const float4*)(k + (size_t)(b*S_ + s0 + row)*512 + h*128);
      const float4* srcv = (const float4*)(v + (size_t)(b*S_ + s0 + row)*512 + h*128);
      float4* dk = (float4*)&ks[row][0];
      float4* dv = (float4*)&vs[row][0];
      #pragma unroll
      for(int c=0;c<4;c++){ dk[c4+c]=srck[c4+c]; dv[c4+c]=srcv[c4+c]; }
      if (tid < TS) gsS[tid] = g[bh*512 + s0 + tid];
    }
    __syncthreads();
    float a00=0,a01=0,a10=0,a11=0;
    {
      const float4* q0 = (const float4*)&qs[i*2][0];
      const float4* q1 = (const float4*)&qs[i*2+1][0];
      const float4* k0 = (const float4*)&ks[j][0];
      const float4* k1 = (const float4*)&ks[j+16][0];
      #pragma unroll
      for(int d4=0; d4<32; ++d4){
        float4 qa=q0[d4], qb=q1[d4], ka=k0[d4], kb=k1[d4];
        a00 += qa.x*ka.x+qa.y*ka.y+qa.z*ka.z+qa.w*ka.w;
        a01 += qa.x*kb.x+qa.y*kb.y+qa.z*kb.z+qa.w*kb.w;
        a10 += qb.x*ka.x+qb.y*ka.y+qb.z*ka.z+qb.w*ka.w;
        a11 += qb.x*kb.x+qb.y*kb.y+qb.z*kb.z+qb.w*kb.w;
      }
    }
    int tA = t0 + i*2, tB = tA+1;
    int sA = s0 + j,   sB = sA + 16;
    float gA = gsS[j], gB = gsS[j+16];
    float mA = MtS[i*2], mB = MtS[i*2+1];
    float w00 = (sA<=tA)? a00*sc*expneg_(gA-mA) : 0.f;
    float w01 = (sB<=tA)? a01*sc*expneg_(gB-mA) : 0.f;
    float w10 = (sA<=tB)? a10*sc*expneg_(gA-mB) : 0.f;
    float w11 = (sB<=tB)? a11*sc*expneg_(gB-mB) : 0.f;
    float r0 = w00+w01, r1 = w10+w11;
    #pragma unroll
    for(int msk=1; msk<16; msk<<=1){ r0 += __shfl_xor(r0,msk,16); r1 += __shfl_xor(r1,msk,16); }
    if (j==0){ lsumS[i*2] += r0; lsumS[i*2+1] += r1; }
    Sw[i*2][j]     = w00; Sw[i*2][j+16]   = w01;
    Sw[i*2+1][j]   = w10; Sw[i*2+1][j+16] = w11;
    __syncthreads();
    #pragma unroll 8
    for(int s=0;s<TS;s++){
      float w0 = Sw[i*2][s], w1 = Sw[i*2+1][s];
      float4 v0 = *(const float4*)&vs[s][j*4];
      float4 v1 = *(const float4*)&vs[s][64+j*4];
      o[0][0]+=w0*v0.x; o[0][1]+=w0*v0.y; o[0][2]+=w0*v0.z; o[0][3]+=w0*v0.w;
      o[0][4]+=w0*v1.x; o[0][5]+=w0*v1.y; o[0][6]+=w0*v1.z; o[0][7]+=w0*v1.w;
      o[1][0]+=w1*v0.x; o[1][1]+=w1*v0.y; o[1][2]+=w1*v0.z; o[1][3]+=w1*v0.w;
      o[1][4]+=w1*v1.x; o[1][5]+=w1*v1.y; o[1][6]+=w1*v1.z; o[1][7]+=w1*v1.w;
    }
  }
  __syncthreads();
  #pragma unroll
  for(int r=0;r<2;r++){
    int tl = i*2+r;
    int t = t0 + tl;
    float maxD = cssS[tl] + MtS[tl];
    float norm = fmaxf(fabsf(lsumS[tl]), expclamp_(-maxD));
    float scale = rcp_(norm+1e-6f);
    float sum=0.f;
    #pragma unroll
    for(int d=0;d<8;d++){ o[r][d]*=scale; sum+=o[r][d]; }
    #pragma unroll
    for(int msk=1; msk<16; msk<<=1) sum += __shfl_xor(sum,msk,16);
    float mu = sum*(1.f/128.f);
    float var=0.f;
    #pragma unroll
    for(int d=0;d<8;d++){ float dd=o[r][d]-mu; var+=dd*dd; }
    #pragma unroll
    for(int msk=1; msk<16; msk<<=1) var += __shfl_xor(var,msk,16);
    float rs = rsqrtf(var*(1.f/128.f)+EPS_);
    if (t < S_){
      float* dst = hflat + (size_t)(b*S_+t)*1024 + h*128;
      #pragma unroll
      for(int c=0;c<4;c++) dst[j*4+c]    = (o[r][c]  -mu)*rs*onw[h*128+j*4+c];
      #pragma unroll
      for(int c=0;c<4;c++) dst[64+j*4+c] = (o[r][4+c]-mu)*rs*onw[h*128+64+j*4+c];
    }
  }
}

// ---------------- hout = (hflat + skip*xc) * silu(z) -> bf16 ----------------
__global__ __launch_bounds__(256) void k_hout(
  const float* __restrict__ A, const float* __restrict__ xc, const float* __restrict__ skip,
  bf16* __restrict__ out16)
{
  int i=blockIdx.x*256+threadIdx.x;
  int r=i/512, c=i%512;
  float hf=A[(size_t)r*1024+c];
  float z =A[(size_t)r*1024+512+c];
  out16[(size_t)r*512+c] = __float2bfloat16((hf + skip[c]*xc[(size_t)r*512+c]) * silu_(z));
}

// ---------------- wx: tiled, transposed weights in registers (coalesced), h-tile in LDS ----------------
// gwT layout: gwT[((g*4+n)*64+d)*64+e] == s_gate_w[g][n][e][d]
#define WXR 64
__global__ __launch_bounds__(256,2) void k_wx(
  const float* __restrict__ h, const float* __restrict__ hc,
  const float* __restrict__ gwT, const float* __restrict__ gb,
  float* __restrict__ wx)
{
  int rt = blockIdx.x, g = blockIdx.y;
  int tid = threadIdx.x;
  int n = tid>>6, e = tid&63;
  const float* src = (g<2)? hc : h;
  __shared__ __align__(16) float hs[WXR][260];
  float W[64];
  #pragma unroll
  for(int d=0;d<64;d++) W[d] = gwT[(size_t)(((g*4+n)*64+d))*64 + e];  // = w[g][n][e][d], lane-coalesced
  float bias = gb[(g*4+n)*64+e];
  int row0 = rt*WXR;
  for(int idx=tid; idx<WXR*64; idx+=256){
    int rr = idx>>6, cc4 = (idx&63)*4;
    *(float4*)&hs[rr][cc4] = *(const float4*)(src + (size_t)(row0+rr)*256 + cc4);
  }
  __syncthreads();
  #pragma unroll 4
  for(int rr=0; rr<WXR; ++rr){
    int r = row0+rr;
    if (r>=NROW) break;
    const float* hrow = &hs[rr][n*64];
    float a0=0,a1=0,a2=0,a3=0;
    #pragma unroll
    for(int d=0;d<64;d+=4){
      float4 hv = *(const float4*)&hrow[d];   // wave-uniform address -> LDS broadcast
      a0+=hv.x*W[d]; a1+=hv.y*W[d+1]; a2+=hv.z*W[d+2]; a3+=hv.w*W[d+3];
    }
    int b=r/S_, s=r%S_;
    wx[((size_t)(b*4+n)*512 + s)*256 + g*64 + e] = bias + ((a0+a1)+(a2+a3));
  }
}

// ---------------- sLSTM scan: readlane matvec + chunked LDS y-buffer ----------------
#define YCH 32
__global__ __launch_bounds__(256,1) void k_scan(
  const float* __restrict__ wx, const float* __restrict__ rw, float* __restrict__ y_out)
{
  int bn = blockIdx.x; int b = bn>>2, n = bn&3;
  int tid = threadIdx.x; int g = tid>>6, e = tid&63;
  float W[64];
  #pragma unroll
  for(int d=0;d<64;d++) W[d]=rw[(size_t)(((g*4+n)*64+d))*64 + e];
  __shared__ float rawS[2][256];
  __shared__ __align__(16) float wxS[2][YCH*256];
  __shared__ float ybuf[YCH*64];
  const float* wxBase = wx + (size_t)bn*512*256;
  { // stage chunk 0
    const float4* src=(const float4*)wxBase;
    float4* dst=(float4*)&wxS[0][0];
    #pragma unroll
    for(int j=0;j<8;j++) dst[j*256+tid]=src[j*256+tid];
  }
  float c=0.f, nn=0.f, m=0.f, yreg=0.f;
  __syncthreads();
  for (int s=0; s<S_; ++s){
    int sl = s & (YCH-1);
    int p  = s & 1;
    float wxv = wxS[(s>>5)&1][sl*256 + tid];
    float a0=0.f,a1=0.f,a2=0.f,a3=0.f;
    #pragma unroll
    for(int d=0; d<64; d+=4){
      a0 += rdlane_(yreg,d  )*W[d  ];
      a1 += rdlane_(yreg,d+1)*W[d+1];
      a2 += rdlane_(yreg,d+2)*W[d+2];
      a3 += rdlane_(yreg,d+3)*W[d+3];
    }
    rawS[p][tid] = wxv + ((a0+a1)+(a2+a3));
    __syncthreads();
    float iraw=rawS[p][e], fraw=rawS[p][64+e], zraw=rawS[p][128+e], oraw=rawS[p][192+e];
    float lfm = m + logsig_(fraw);
    float mnew = fmaxf(iraw, lfm);
    float ig = expneg_(iraw-mnew), fg=expneg_(lfm-mnew);
    c  = fg*c  + ig*tanh_(zraw);
    nn = fmaxf(fg*nn + ig, 1e-30f);
    float y = sig_(oraw) * c * rcp_(nn);
    m = mnew;
    yreg = y;
    if (g==0) ybuf[sl*64+e] = y;
    if (sl==YCH-1 || s==S_-1){
      __syncthreads();                    // make wave-0's ybuf writes visible
      int s0 = s-sl;
      int cnt = (sl+1)*64;
      for(int idx=tid; idx<cnt; idx+=256){
        int ss=s0+(idx>>6), ee=idx&63;
        y_out[((size_t)b*S_+ss)*256 + n*64 + ee] = ybuf[idx];
      }
      int nch=(s>>5)+1;
      if (nch<16){
        const float4* src=(const float4*)(wxBase+(size_t)nch*YCH*256);
        float4* dst=(float4*)&wxS[nch&1][0];
        #pragma unroll
        for(int j=0;j<8;j++) dst[j*256+tid]=src[j*256+tid];
      }
      __syncthreads();                    // WAR-protect ybuf + publish next wx chunk
    }
  }
}

// ---------------- yn-add + fused LN2 -> bf16 ----------------
__global__ __launch_bounds__(256) void k_ynadd_ln2(
  const float* __restrict__ y, const float* __restrict__ gn,
  float* __restrict__ x, const float* __restrict__ ln2w, bf16* __restrict__ h16)
{
  __shared__ float red[256];
  int r=blockIdx.x, t=threadIdx.x;
  float xv = x[(size_t)r*256+t];
  if (r < NROW){
    float v=y[(size_t)r*256+t];
    float s=v;
    for(int m=32;m;m>>=1) s+=__shfl_xor(s,m,64);
    float mu=s*(1.f/64.f);
    float d=v-mu;
    float q=d*d;
    for(int m=32;m;m>>=1) q+=__shfl_xor(q,m,64);
    float var=q*(1.f/64.f);
    xv += d*rsqrtf(var+EPS_)*gn[t];
    x[(size_t)r*256+t]=xv;
  }
  red[t]=xv; __syncthreads();
  for(int s=128;s>0;s>>=1){ if(t<s) red[t]+=red[t+s]; __syncthreads(); }
  float mu2=red[0]*(1.f/E_); __syncthreads();
  float dd=xv-mu2;
  red[t]=dd*dd; __syncthreads();
  for(int s=128;s>0;s>>=1){ if(t<s) red[t]+=red[t+s]; __syncthreads(); }
  float var2=red[0]*(1.f/E_);
  h16[(size_t)r*256+t]=__float2bfloat16(dd*rsqrtf(var2+EPS_)*ln2w[t]);
}

// ---------------- ffn gate: relu(gate)*upf -> bf16 ----------------
__global__ __launch_bounds__(256) void k_ffmul(const float* __restrict__ ffu, bf16* __restrict__ out)
{
  int i=blockIdx.x*256+threadIdx.x;
  int r=i/384, j=i%384;
  out[(size_t)r*384+j] = __float2bfloat16(fmaxf(ffu[(size_t)r*768+j],0.f)*ffu[(size_t)r*768+384+j]);
}

// ---------------- fused postnorm-LN + cq build -> bf16 ----------------
__global__ __launch_bounds__(256) void k_cq_ln(
  const float* __restrict__ x, const float* __restrict__ pw,
  const float* __restrict__ qe, const float* __restrict__ pide, const int* __restrict__ tgt,
  bf16* __restrict__ cq)
{
  __shared__ float red[256];
  int r=blockIdx.x, t=threadIdx.x;
  float v = x[(size_t)r*256+t];
  red[t]=v; __syncthreads();
  for(int s=128;s>0;s>>=1){ if(t<s) red[t]+=red[t+s]; __syncthreads(); }
  float mu=red[0]*(1.f/E_); __syncthreads();
  float d=v-mu;
  red[t]=d*d; __syncthreads();
  for(int s=128;s>0;s>>=1){ if(t<s) red[t]+=red[t+s]; __syncthreads(); }
  float var=red[0]*(1.f/E_);
  float dv = d*rsqrtf(var+EPS_)*pw[t];
  float pe=pide[r]; int tg=tgt[r];
  size_t base=(size_t)r*1024;
  cq[base+t]=__float2bfloat16(dv-pe);
  cq[base+256+t]=__float2bfloat16(qe[(size_t)r*256+t]);
  cq[base+512+t]=__float2bfloat16((tg==1)? dv:0.f);
  cq[base+768+t]=__float2bfloat16((tg==0)? dv:0.f);
}

// ---------------- final: selected logit + sigmoid ----------------
__global__ __launch_bounds__(256) void k_final(
  const float* __restrict__ o2, const float* __restrict__ w3, const float* __restrict__ b3,
  const int* __restrict__ qsh, float* __restrict__ out)
{
  __shared__ float red[256];
  int r=blockIdx.x, t=threadIdx.x;
  int qi=qsh[r];
  float p=o2[(size_t)r*256+t]*w3[(size_t)qi*256+t];
  red[t]=p; __syncthreads();
  for(int s=128;s>0;s>>=1){ if(t<s) red[t]+=red[t+s]; __syncthreads(); }
  if(t==0) out[r]=sig_(red[0]+b3[qi]);
}

// ---------------- launch ----------------
extern "C" void kernel_launch(void* const* d_in, const int* in_sizes, int n_in,
                              void* d_out, int out_size, void* d_ws, size_t ws_size,
                              hipStream_t stream) {
  const int* questions = (const int*)d_in[0];
  const int* responses = (const int*)d_in[1];
  const int* skills    = (const int*)d_in[2];
  const float* q_embed       = (const float*)d_in[4];
  const float* qa_embed      = (const float*)d_in[5];
  const float* q_embed_diff  = (const float*)d_in[6];
  const float* qa_embed_diff = (const float*)d_in[7];
  const float* difficult_param=(const float*)d_in[8];
  const float* ln0_w   = (const float*)d_in[9];
  const float* m_up_w  = (const float*)d_in[10];
  const float* m_up_b  = (const float*)d_in[11];
  const float* m_conv_w= (const float*)d_in[12];
  const float* m_conv_b= (const float*)d_in[13];
  const float* m_q_w   = (const float*)d_in[14];
  const float* m_k_w   = (const float*)d_in[15];
  const float* m_v_w   = (const float*)d_in[16];
  const float* m_ig_w  = (const float*)d_in[17];
  const float* m_ig_b  = (const float*)d_in[18];
  const float* m_fg_w  = (const float*)d_in[19];
  const float* m_fg_b  = (const float*)d_in[20];
  const float* m_outnorm_w=(const float*)d_in[21];
  const float* m_skip  = (const float*)d_in[22];
  const float* m_down_w= (const float*)d_in[23];
  const float* m_down_b= (const float*)d_in[24];
  const float* ln1_w   = (const float*)d_in[25];
  const float* s_conv_w= (const float*)d_in[26];
  const float* s_conv_b= (const float*)d_in[27];
  const float* s_gate_w= (const float*)d_in[28];
  const float* s_rec_w = (const float*)d_in[29];
  const float* s_bias  = (const float*)d_in[30];
  const float* s_gn_w  = (const float*)d_in[31];
  const float* ln2_w   = (const float*)d_in[32];
  const float* ffn_up_w= (const float*)d_in[33];
  const float* ffn_up_b= (const float*)d_in[34];
  const float* ffn_down_w=(const float*)d_in[35];
  const float* ffn_down_b=(const float*)d_in[36];
  const float* postnorm_w=(const float*)d_in[37];
  const float* out_w1  = (const float*)d_in[38];
  const float* out_b1  = (const float*)d_in[39];
  const float* out_w2  = (const float*)d_in[40];
  const float* out_b2  = (const float*)d_in[41];
  const float* out_w3  = (const float*)d_in[42];
  const float* out_b3  = (const float*)d_in[43];

  float* ws = (float*)d_ws;
  const size_t R = (size_t)NP_*256;
  float* x    = ws;
  float* qe   = ws + R;
  float* h    = ws + 2*R;
  float* t256 = ws + 3*R;        // early: split-bf16 LN0 output (h_hi/h_lo); late: out_w2 result
  float* A    = ws + 4*R;        // NP x 1024 ; also scan-layout wx
  float* Bb   = ws + 8*R;        // NP x 512
  float* Cb   = ws + 10*R;       // NP x 512  (q; later y_out; later b16)
  float* Db   = ws + 12*R;       // NP x 512  (k; later hout16 / ffg16)
  float* Eb   = ws + 14*R;       // NP x 512  (v; later cq16)
  float* pide = ws + 16*R;
  int*   tgt  = (int*)(ws + 16*R + NP_);
  int*   qsh  = (int*)(ws + 16*R + 2*NP_);
  float* igb  = ws + 16*R + 3*NP_;
  float* fgb  = igb + 64*512;
  float* cs1  = fgb + 64*512;
  float* gdec = cs1 + 64*512;
  float* Mrun = gdec + 64*512;
  bf16* wpool = (bf16*)(Mrun + 64*512);
  bf16* m_down_w16  = wpool;
  bf16* ffn_up_w16  = m_down_w16 + 256*512;
  bf16* ffn_down_w16= ffn_up_w16 + 768*256;
  bf16* out_w1_16   = ffn_down_w16 + 256*384;
  bf16* out_w2_16   = out_w1_16 + 512*1024;
  bf16* h16         = out_w2_16 + 256*512;
  bf16* m_up_whi    = h16 + (size_t)NP_*256;     // 1024*256
  bf16* m_up_wlo    = m_up_whi + 1024*256;       // 1024*256
  float* gwT        = (float*)(m_up_wlo + 1024*256);  // 16*64*64 floats (256 KB)
  bf16* hout16 = (bf16*)Db;
  bf16* ffg16  = (bf16*)Db;
  bf16* cq16   = (bf16*)Eb;
  bf16* b16    = (bf16*)Cb;
  bf16* h_hi   = (bf16*)t256;                    // NP*256
  bf16* h_lo   = h_hi + (size_t)NP_*256;         // NP*256 (fits in t256's R floats)

  // ---- one-time weight conversions ----
  k_cvt16<<<(256*512+255)/256,256,0,stream>>>(m_down_w,  m_down_w16,  256*512);
  k_cvt16<<<(768*256+255)/256,256,0,stream>>>(ffn_up_w,  ffn_up_w16,  768*256);
  k_cvt16<<<(256*384+255)/256,256,0,stream>>>(ffn_down_w,ffn_down_w16,256*384);
  k_cvt16<<<(512*1024+255)/256,256,0,stream>>>(out_w1,   out_w1_16,   512*1024);
  k_cvt16<<<(256*512+255)/256,256,0,stream>>>(out_w2,    out_w2_16,   256*512);
  k_cvtsplit<<<(1024*256+255)/256,256,0,stream>>>(m_up_w, m_up_whi, m_up_wlo, 1024*256);
  k_wtrans<<<(16*64*64)/256,256,0,stream>>>(s_gate_w, gwT);

  // ---- embeddings (+LN0 -> split bf16) ----
  k_embed<<<NP_,256,0,stream>>>(questions,responses,skills,q_embed,qa_embed,
      q_embed_diff,qa_embed_diff,difficult_param, ln0_w, x,qe, h_hi,h_lo, pide,tgt,qsh);
  // ---- block M ----
  k_gemm16s<<<dim3(1024/64,NP_/64),256,0,stream>>>(h_hi,h_lo, m_up_whi,m_up_wlo, m_up_b, A, 1024,256);
  k_conv_silu<<<(NP_*512)/256,256,0,stream>>>(A,1024, m_conv_w,m_conv_b, Bb,512,512);
  k_headwise<<<(NP_*512)/256,256,0,stream>>>(Bb, A,1024, m_q_w,m_k_w,m_v_w, Cb,Db,Eb);
  k_igfg<<<NROW,256,0,stream>>>(Cb,Db,Eb, m_ig_w,m_ig_b,m_fg_w,m_fg_b, igb,fgb);
  k_decay<<<64,256,0,stream>>>(igb,fgb, cs1,gdec,Mrun);
  k_attn<<<dim3((S_+TQ-1)/TQ, B_*NH_),256,0,stream>>>(Cb,Db,Eb, cs1,gdec,Mrun, m_outnorm_w, A);
  k_hout<<<(NP_*512)/256,256,0,stream>>>(A, Bb, m_skip, hout16);
  k_gemm16<<<dim3(256/64,NP_/64),256,0,stream>>>(hout16, m_down_w16, m_down_b, x, x, (bf16*)nullptr, 256,512,0);
  // ---- block S ----
  k_ln<<<NP_,256,0,stream>>>(x, ln1_w, h);
  k_conv_silu<<<(NP_*256)/256,256,0,stream>>>(h,256, s_conv_w,s_conv_b, Bb,256,256);
  k_wx<<<dim3(128,4),256,0,stream>>>(h, Bb, gwT, s_bias, A);
  k_scan<<<64,256,0,stream>>>(A, s_rec_w, Cb);
  k_ynadd_ln2<<<NP_,256,0,stream>>>(Cb, s_gn_w, x, ln2_w, h16);
  // ---- FFN ----
  k_gemm16<<<dim3(768/64,NP_/64),256,0,stream>>>(h16, ffn_up_w16, ffn_up_b, (const float*)nullptr, A, (bf16*)nullptr, 768,256,0);
  k_ffmul<<<(NP_*384)/256,256,0,stream>>>(A, ffg16);
  k_gemm16<<<dim3(256/64,NP_/64),256,0,stream>>>(ffg16, ffn_down_w16, ffn_down_b, x, x, (bf16*)nullptr, 256,384,0);
  // ---- output head ----
  k_cq_ln<<<NP_,256,0,stream>>>(x, postnorm_w, qe, pide, tgt, cq16);
  k_gemm16<<<dim3(512/64,NP_/64),256,0,stream>>>(cq16, out_w1_16, out_b1, (const float*)nullptr, (float*)nullptr, b16, 512,1024,1);
  k_gemm16<<<dim3(256/64,NP_/64),256,0,stream>>>(b16, out_w2_16, out_b2, (const float*)nullptr, t256, (bf16*)nullptr, 256,512,1);
  k_final<<<NROW,256,0,stream>>>(t256, out_w3, out_b3, qsh, (float*)d_out);
}